// Round 1
// baseline (2286.032 us; speedup 1.0000x reference)
//
#include <hip/hip_runtime.h>
#include <hip/hip_bf16.h>
#include <math.h>

#define T_  6
#define NN  4096
#define XD_ 64
#define H_  256
#define ZZ  128
#define EE  131072

// ---------------------------------------------------------------- degree hist
__global__ void k_deg(const int* __restrict__ rows, int* __restrict__ degcnt) {
    int e = blockIdx.x * 256 + threadIdx.x;
    atomicAdd(&degcnt[rows[e]], 1);
}

// ------------------------------------------- scan (CSR offsets) + dinv, 1 blk
__global__ void k_scan_dinv(const int* __restrict__ degcnt,
                            int* __restrict__ row_start,
                            int* __restrict__ cursor,
                            float* __restrict__ dinv) {
    __shared__ int sbuf[1024];
    int t = threadIdx.x;
    int b = t * 4;
    int v0 = degcnt[b + 0], v1 = degcnt[b + 1], v2 = degcnt[b + 2], v3 = degcnt[b + 3];
    dinv[b + 0] = rsqrtf((float)(v0 + 1));   // +1: self loop
    dinv[b + 1] = rsqrtf((float)(v1 + 1));
    dinv[b + 2] = rsqrtf((float)(v2 + 1));
    dinv[b + 3] = rsqrtf((float)(v3 + 1));
    int s = v0 + v1 + v2 + v3;
    sbuf[t] = s;
    __syncthreads();
    for (int off = 1; off < 1024; off <<= 1) {
        int x = sbuf[t];
        int y = (t >= off) ? sbuf[t - off] : 0;
        __syncthreads();
        sbuf[t] = x + y;
        __syncthreads();
    }
    int excl = sbuf[t] - s;
    int r0 = excl, r1 = excl + v0, r2 = r1 + v1, r3 = r2 + v2;
    row_start[b + 0] = r0; cursor[b + 0] = r0;
    row_start[b + 1] = r1; cursor[b + 1] = r1;
    row_start[b + 2] = r2; cursor[b + 2] = r2;
    row_start[b + 3] = r3; cursor[b + 3] = r3;
    if (t == 1023) row_start[NN] = r3 + v3;
}

// ------------------------------------------------------------- CSR scatter
__global__ void k_scatter(const int* __restrict__ rows, const int* __restrict__ cols,
                          int* __restrict__ cursor, const float* __restrict__ dinv,
                          int* __restrict__ col_idx, float* __restrict__ val) {
    int e = blockIdx.x * 256 + threadIdx.x;
    int r = rows[e], cc = cols[e];
    int pos = atomicAdd(&cursor[r], 1);
    col_idx[pos] = cc;
    val[pos] = dinv[r] * dinv[cc];
}

// ------------------------------------------------- SpMM: out = S @ Y, C = 256
// one wave per row; lane holds float4 of columns. Y is [N,256] row-major.
__global__ void k_spmm(const float* __restrict__ Y,
                       const int* __restrict__ row_start,
                       const int* __restrict__ col_idx,
                       const float* __restrict__ val,
                       const float* __restrict__ dinv,
                       float* __restrict__ out, int ldo,
                       float* __restrict__ out2) {
    int lane = threadIdx.x & 63;
    int wave = threadIdx.x >> 6;
    int r = (blockIdx.x << 2) + wave;
    float dr = dinv[r];
    float sc = dr * dr;
    const float4* yr = (const float4*)(Y + (size_t)r * H_);
    float4 a = yr[lane];
    float4 acc = make_float4(a.x * sc, a.y * sc, a.z * sc, a.w * sc);
    int s0 = row_start[r], s1 = row_start[r + 1];
    for (int i = s0; i < s1; ++i) {
        int cc = col_idx[i];
        float v = val[i];
        const float4* yc = (const float4*)(Y + (size_t)cc * H_);
        float4 y = yc[lane];
        acc.x += v * y.x; acc.y += v * y.y; acc.z += v * y.z; acc.w += v * y.w;
    }
    *((float4*)(out + (size_t)r * ldo + lane * 4)) = acc;
    if (out2)
        *((float4*)(out2 + (size_t)r * ldo + lane * 4)) = acc;
}

// ------------------------------------------------------- generic f32 GEMM
// C[M,N] = act(A[M,K] @ B[K,N] + bias (+ C if accum)); tiles 64x64, 256 thr.
// grid: (N/64, M/64, batch); per-batch B += strideB, C += strideC.
// act: 0 none, 1 relu, 2 softplus
__launch_bounds__(256)
__global__ void k_gemm(const float* __restrict__ A, int lda,
                       const float* __restrict__ B, int ldb,
                       float* __restrict__ C, int ldc,
                       int K, const float* __restrict__ bias,
                       int act, int accum,
                       long long strideB, long long strideC) {
    __shared__ float As[16][68];   // [k][m], pad 4 -> <=2-way bank conflicts
    __shared__ float Bs[16][68];   // [k][n]
    int tid = threadIdx.x;
    const float* Bp = B + (size_t)blockIdx.z * strideB;
    float* Cp = C + (size_t)blockIdx.z * strideC;
    int row0 = blockIdx.y * 64;
    int col0 = blockIdx.x * 64;
    int ti = tid >> 4;           // 0..15 row group
    int tj = tid & 15;           // 0..15 col group
    int am = tid >> 2;           // 0..63 A row
    int ak = (tid & 3) << 2;     // 0,4,8,12
    int br = tid >> 4;           // 0..15 B k-row
    int bc = (tid & 15) << 2;    // 0..60
    const float* Aload = A + (size_t)(row0 + am) * lda + ak;
    const float* Bload = Bp + (size_t)br * ldb + col0 + bc;
    float acc[4][4] = {};
    for (int k0 = 0; k0 < K; k0 += 16) {
        float4 av = *(const float4*)(Aload + k0);
        float4 bv = *(const float4*)(Bload + (size_t)k0 * ldb);
        As[ak + 0][am] = av.x;
        As[ak + 1][am] = av.y;
        As[ak + 2][am] = av.z;
        As[ak + 3][am] = av.w;
        *(float4*)&Bs[br][bc] = bv;
        __syncthreads();
#pragma unroll
        for (int kk = 0; kk < 16; ++kk) {
            float4 a = *(const float4*)&As[kk][ti << 2];
            float4 b = *(const float4*)&Bs[kk][tj << 2];
            acc[0][0] += a.x * b.x; acc[0][1] += a.x * b.y; acc[0][2] += a.x * b.z; acc[0][3] += a.x * b.w;
            acc[1][0] += a.y * b.x; acc[1][1] += a.y * b.y; acc[1][2] += a.y * b.z; acc[1][3] += a.y * b.w;
            acc[2][0] += a.z * b.x; acc[2][1] += a.z * b.y; acc[2][2] += a.z * b.z; acc[2][3] += a.z * b.w;
            acc[3][0] += a.w * b.x; acc[3][1] += a.w * b.y; acc[3][2] += a.w * b.z; acc[3][3] += a.w * b.w;
        }
        __syncthreads();
    }
#pragma unroll
    for (int r = 0; r < 4; ++r) {
        int row = row0 + (ti << 2) + r;
        float4 v = make_float4(acc[r][0], acc[r][1], acc[r][2], acc[r][3]);
        float* cp = Cp + (size_t)row * ldc + col0 + (tj << 2);
        if (bias) {
            const float* bp = bias + col0 + (tj << 2);
            v.x += bp[0]; v.y += bp[1]; v.z += bp[2]; v.w += bp[3];
        }
        if (accum) {
            float4 o = *(const float4*)cp;
            v.x += o.x; v.y += o.y; v.z += o.z; v.w += o.w;
        }
        if (act == 1) {
            v.x = fmaxf(v.x, 0.f); v.y = fmaxf(v.y, 0.f);
            v.z = fmaxf(v.z, 0.f); v.w = fmaxf(v.w, 0.f);
        } else if (act == 2) {
            v.x = (v.x > 20.f) ? v.x : log1pf(expf(v.x));
            v.y = (v.y > 20.f) ? v.y : log1pf(expf(v.y));
            v.z = (v.z > 20.f) ? v.z : log1pf(expf(v.z));
            v.w = (v.w > 20.f) ? v.w : log1pf(expf(v.w));
        }
        *(float4*)cp = v;
    }
}

// ------------------------------------------------ z = eps*std + mu
__global__ void k_z(const float* __restrict__ eps_t, const float* __restrict__ stdv,
                    const float* __restrict__ mu, float* __restrict__ z) {
    int i = blockIdx.x * 256 + threadIdx.x;
    z[i] = eps_t[i] * stdv[i] + mu[i];
}

// ------------------------------------------------ LSTM elementwise update
__global__ void k_lstm(const float* __restrict__ G, float* __restrict__ h,
                       float* __restrict__ c) {
    int idx = blockIdx.x * 256 + threadIdx.x;       // over N*H
    int n = idx >> 8, j = idx & 255;
    const float* g = G + (size_t)n * 1024;
    float gi = 1.f / (1.f + expf(-g[j]));
    float gf = 1.f / (1.f + expf(-g[256 + j]));
    float go = 1.f / (1.f + expf(-g[512 + j]));
    float ct = tanhf(g[768 + j]);
    float ho = h[idx], co = c[idx];
    float cn = gf * ho + gi * ct;   // faithful: F*h_old
    float hn = go * tanhf(co);      // faithful: uses old c
    h[idx] = hn;
    c[idx] = cn;
}

// ------------------------------------------------ dec helpers
__global__ void k_zdrop(const float* __restrict__ du, const float* __restrict__ z,
                        float* __restrict__ zd) {
    int i = blockIdx.x * 256 + threadIdx.x;
    zd[i] = (du[i] < 0.5f) ? z[i] * 2.f : 0.f;
}

__global__ void k_transpose(const float* __restrict__ zd, float* __restrict__ zdT) {
    int idx = blockIdx.x * 256 + threadIdx.x;      // over Z*N, idx = k*N+n
    int n = idx & (NN - 1);
    int k = idx >> 12;
    zdT[idx] = zd[(size_t)n * ZZ + k];
}

__global__ void k_copy4(const float* __restrict__ src, float* __restrict__ dst) {
    int i = blockIdx.x * 256 + threadIdx.x;
    ((float4*)dst)[i] = ((const float4*)src)[i];
}

// ============================================================================
extern "C" void kernel_launch(void* const* d_in, const int* in_sizes, int n_in,
                              void* d_out_v, int out_size, void* d_ws, size_t ws_size,
                              hipStream_t stream) {
    const float* x         = (const float*)d_in[0];
    const int*   edges     = (const int*)d_in[1];
    const float* eps       = (const float*)d_in[2];
    const float* drop_u    = (const float*)d_in[3];
    const float* phi_x_w   = (const float*)d_in[4];
    const float* phi_x_b   = (const float*)d_in[5];
    const float* phi_z_w   = (const float*)d_in[6];
    const float* phi_z_b   = (const float*)d_in[7];
    const float* enc_w     = (const float*)d_in[8];
    const float* enc_mu_w  = (const float*)d_in[9];
    const float* enc_lv_w  = (const float*)d_in[10];
    const float* prior_w   = (const float*)d_in[11];
    const float* prior_b   = (const float*)d_in[12];
    const float* prior_mu_w = (const float*)d_in[13];
    const float* prior_mu_b = (const float*)d_in[14];
    // d_in[15], d_in[16] (prior_lv_*) are dead in the returned outputs
    const float* gru_wx    = (const float*)d_in[17];
    const float* gru_wh    = (const float*)d_in[18];
    float* out = (float*)d_out_v;

    float* ws = (float*)d_ws;
    size_t o = 0;
    float* dinv      = ws + o; o += NN;
    int*   degcnt    = (int*)(ws + o); o += NN;
    int*   row_start = (int*)(ws + o); o += NN + 4;
    int*   cursor    = (int*)(ws + o); o += NN;
    int*   col_idx   = (int*)(ws + o); o += EE;
    float* val       = ws + o; o += EE;
    float* h         = ws + o; o += (size_t)NN * H_;
    float* c         = ws + o; o += (size_t)NN * H_;
    float* phi_x     = ws + o; o += (size_t)NN * H_;   // reused as phi_z
    float* enc_t     = ws + o; o += (size_t)NN * H_;
    float* SEb       = ws + o; o += (size_t)NN * H_;
    float* prior_t   = ws + o; o += (size_t)NN * H_;   // reused as zd
    float* XIN1      = ws + o; o += (size_t)NN * 512;  // [S@phi_x | S@h]
    float* XIN2      = ws + o; o += (size_t)NN * 512;  // [S@phi_x | S@phi_z]
    float* enc_std   = ws + o; o += (size_t)NN * ZZ;
    float* zbuf      = ws + o; o += (size_t)NN * ZZ;
    float* Gpre      = ws + o; o += (size_t)NN * 1024; // reused as zdT
    if (ws_size < o * sizeof(float)) return;           // insufficient scratch

    const size_t NZ = (size_t)NN * ZZ;
    const size_t HOFF = (size_t)2 * T_ * NZ;           // h output offset
    const size_t DECOFF = HOFF + (size_t)NN * H_;      // dec output offset

    hipMemsetAsync(h, 0, (size_t)NN * H_ * sizeof(float), stream);
    hipMemsetAsync(c, 0, (size_t)NN * H_ * sizeof(float), stream);

    for (int t = 0; t < T_; ++t) {
        const int* rows = edges + (size_t)t * 2 * EE;
        const int* cols = rows + EE;

        // ---- per-step normalized adjacency in CSR
        hipMemsetAsync(degcnt, 0, NN * sizeof(int), stream);
        k_deg<<<EE / 256, 256, 0, stream>>>(rows, degcnt);
        k_scan_dinv<<<1, 1024, 0, stream>>>(degcnt, row_start, cursor, dinv);
        k_scatter<<<EE / 256, 256, 0, stream>>>(rows, cols, cursor, dinv, col_idx, val);

        // ---- phi_x = relu(x[t] @ phi_x_w + b)
        k_gemm<<<dim3(H_ / 64, NN / 64, 1), 256, 0, stream>>>(
            x + (size_t)t * NN * XD_, XD_, phi_x_w, H_, phi_x, H_, XD_,
            phi_x_b, 1, 0, 0, 0);

        // ---- SX = S@phi_x  (into XIN1[:, :256] and XIN2[:, :256])
        k_spmm<<<NN / 4, 256, 0, stream>>>(phi_x, row_start, col_idx, val, dinv,
                                           XIN1, 512, XIN2);
        // ---- SH = S@h      (into XIN1[:, 256:])
        k_spmm<<<NN / 4, 256, 0, stream>>>(h, row_start, col_idx, val, dinv,
                                           XIN1 + 256, 512, nullptr);

        // ---- enc_t = relu([SX|SH] @ enc_w)
        k_gemm<<<dim3(4, 64, 1), 256, 0, stream>>>(XIN1, 512, enc_w, H_,
                                                   enc_t, H_, 512, nullptr, 1, 0, 0, 0);
        // ---- SE = S@enc_t
        k_spmm<<<NN / 4, 256, 0, stream>>>(enc_t, row_start, col_idx, val, dinv,
                                           SEb, H_, nullptr);
        // ---- enc_mu -> out ; enc_std = softplus(SE @ enc_lv_w)
        k_gemm<<<dim3(2, 64, 1), 256, 0, stream>>>(SEb, H_, enc_mu_w, ZZ,
                                                   out + (size_t)t * NZ, ZZ, H_,
                                                   nullptr, 0, 0, 0, 0);
        k_gemm<<<dim3(2, 64, 1), 256, 0, stream>>>(SEb, H_, enc_lv_w, ZZ,
                                                   enc_std, ZZ, H_, nullptr, 2, 0, 0, 0);
        // ---- prior (lv branch is dead)
        k_gemm<<<dim3(4, 64, 1), 256, 0, stream>>>(h, H_, prior_w, H_,
                                                   prior_t, H_, H_, prior_b, 1, 0, 0, 0);
        k_gemm<<<dim3(2, 64, 1), 256, 0, stream>>>(prior_t, H_, prior_mu_w, ZZ,
                                                   out + (size_t)(T_ + t) * NZ, ZZ, H_,
                                                   prior_mu_b, 0, 0, 0, 0);
        // ---- z = eps*std + mu
        k_z<<<NN * ZZ / 256, 256, 0, stream>>>(eps + (size_t)t * NZ, enc_std,
                                               out + (size_t)t * NZ, zbuf);
        // ---- phi_z = relu(z @ phi_z_w + b)   (reuses phi_x buffer)
        k_gemm<<<dim3(4, 64, 1), 256, 0, stream>>>(zbuf, ZZ, phi_z_w, H_,
                                                   phi_x, H_, ZZ, phi_z_b, 1, 0, 0, 0);
        // ---- SZ = S@phi_z  (into XIN2[:, 256:])
        k_spmm<<<NN / 4, 256, 0, stream>>>(phi_x, row_start, col_idx, val, dinv,
                                           XIN2 + 256, 512, nullptr);

        // ---- gates: Gpre = [SX|SZ] @ Wx_g  (+)  SH @ Wh_g, batched over g
        k_gemm<<<dim3(4, 64, 4), 256, 0, stream>>>(XIN2, 512, gru_wx, H_,
                                                   Gpre, 1024, 512, nullptr, 0, 0,
                                                   (long long)512 * H_, 256);
        k_gemm<<<dim3(4, 64, 4), 256, 0, stream>>>(XIN1 + 256, 512, gru_wh, H_,
                                                   Gpre, 1024, 256, nullptr, 0, 1,
                                                   (long long)H_ * H_, 256);
        // ---- LSTM state update
        k_lstm<<<NN * H_ / 256, 256, 0, stream>>>(Gpre, h, c);
    }

    // ---- final h -> out
    k_copy4<<<NN * H_ / 1024, 256, 0, stream>>>(h, out + HOFF);

    // ---- dec = z_drop @ z_drop.T at t = T-1
    float* zd = prior_t;
    float* zdT = Gpre;
    k_zdrop<<<NN * ZZ / 256, 256, 0, stream>>>(drop_u + (size_t)(T_ - 1) * NZ, zbuf, zd);
    k_transpose<<<NN * ZZ / 256, 256, 0, stream>>>(zd, zdT);
    k_gemm<<<dim3(NN / 64, NN / 64, 1), 256, 0, stream>>>(zd, ZZ, zdT, NN,
                                                          out + DECOFF, NN, ZZ,
                                                          nullptr, 0, 0, 0, 0);
}

// Round 2
// 824.737 us; speedup vs baseline: 2.7718x; 2.7718x over previous
//
#include <hip/hip_runtime.h>
#include <hip/hip_bf16.h>
#include <math.h>

#define T_  6
#define NN  4096
#define XD_ 64
#define H_  256
#define ZZ  128
#define EE  131072

typedef unsigned short u16;
typedef __attribute__((ext_vector_type(8))) short short8;
typedef __attribute__((ext_vector_type(4))) float f32x4;

__device__ __forceinline__ float bf2f(u16 u) { return __uint_as_float(((unsigned)u) << 16); }
__device__ __forceinline__ u16 f2bf(float f) {
    unsigned x = __float_as_uint(f);
    return (u16)((x + 0x7FFFu + ((x >> 16) & 1u)) >> 16);   // RTNE
}

// ---------------------------------------------------------------- degree hist
__global__ void k_deg(const int* __restrict__ rows, int* __restrict__ degcnt) {
    int e = blockIdx.x * 256 + threadIdx.x;
    atomicAdd(&degcnt[rows[e]], 1);
}

// ------------------------------------------- scan (CSR offsets) + dinv, 1 blk
__global__ void k_scan_dinv(const int* __restrict__ degcnt,
                            int* __restrict__ row_start,
                            int* __restrict__ cursor,
                            float* __restrict__ dinv) {
    __shared__ int sbuf[1024];
    int t = threadIdx.x;
    int b = t * 4;
    int v0 = degcnt[b + 0], v1 = degcnt[b + 1], v2 = degcnt[b + 2], v3 = degcnt[b + 3];
    dinv[b + 0] = rsqrtf((float)(v0 + 1));   // +1: self loop
    dinv[b + 1] = rsqrtf((float)(v1 + 1));
    dinv[b + 2] = rsqrtf((float)(v2 + 1));
    dinv[b + 3] = rsqrtf((float)(v3 + 1));
    int s = v0 + v1 + v2 + v3;
    sbuf[t] = s;
    __syncthreads();
    for (int off = 1; off < 1024; off <<= 1) {
        int x = sbuf[t];
        int y = (t >= off) ? sbuf[t - off] : 0;
        __syncthreads();
        sbuf[t] = x + y;
        __syncthreads();
    }
    int excl = sbuf[t] - s;
    int r0 = excl, r1 = excl + v0, r2 = r1 + v1, r3 = r2 + v2;
    row_start[b + 0] = r0; cursor[b + 0] = r0;
    row_start[b + 1] = r1; cursor[b + 1] = r1;
    row_start[b + 2] = r2; cursor[b + 2] = r2;
    row_start[b + 3] = r3; cursor[b + 3] = r3;
    if (t == 1023) row_start[NN] = r3 + v3;
}

// ------------------------------------------------------------- CSR scatter
__global__ void k_scatter(const int* __restrict__ rows, const int* __restrict__ cols,
                          int* __restrict__ cursor, const float* __restrict__ dinv,
                          int* __restrict__ col_idx, float* __restrict__ val) {
    int e = blockIdx.x * 256 + threadIdx.x;
    int r = rows[e], cc = cols[e];
    int pos = atomicAdd(&cursor[r], 1);
    col_idx[pos] = cc;
    val[pos] = dinv[r] * dinv[cc];
}

// ------------------------------------------------- SpMM (bf16): out = S @ Y
// one block per row; 4 waves split the edge list; lane owns 4 of 256 cols.
// optional second input Y2 (same S) -> out2.
__global__ void k_spmm(const u16* __restrict__ Y1, const u16* __restrict__ Y2,
                       const int* __restrict__ row_start, const int* __restrict__ col_idx,
                       const float* __restrict__ val, const float* __restrict__ dinv,
                       u16* __restrict__ out1, u16* __restrict__ out2, int ldo) {
    __shared__ float red[2][4][64][4];
    int lane = threadIdx.x & 63, w = threadIdx.x >> 6;
    int r = blockIdx.x;
    int s0 = row_start[r], s1 = row_start[r + 1];
    int deg = s1 - s0;
    int e0 = s0 + ((deg * w) >> 2);
    int e1 = s0 + ((deg * (w + 1)) >> 2);
    float a1[4] = {0.f, 0.f, 0.f, 0.f};
    float a2[4] = {0.f, 0.f, 0.f, 0.f};
    for (int base = e0; base < e1; base += 64) {
        int n = e1 - base; if (n > 64) n = 64;
        int cl = 0; float vl = 0.f;
        if (base + lane < e1) { cl = col_idx[base + lane]; vl = val[base + lane]; }
        for (int e = 0; e < n; ++e) {
            int cc = __shfl(cl, e);
            float v = __shfl(vl, e);
            ushort4 y = *(const ushort4*)(Y1 + (size_t)cc * H_ + lane * 4);
            a1[0] += v * bf2f(y.x); a1[1] += v * bf2f(y.y);
            a1[2] += v * bf2f(y.z); a1[3] += v * bf2f(y.w);
            if (Y2) {
                ushort4 y2 = *(const ushort4*)(Y2 + (size_t)cc * H_ + lane * 4);
                a2[0] += v * bf2f(y2.x); a2[1] += v * bf2f(y2.y);
                a2[2] += v * bf2f(y2.z); a2[3] += v * bf2f(y2.w);
            }
        }
    }
#pragma unroll
    for (int j = 0; j < 4; ++j) { red[0][w][lane][j] = a1[j]; red[1][w][lane][j] = a2[j]; }
    __syncthreads();
    if (w == 0) {
        float dr = dinv[r], sc = dr * dr;
#pragma unroll
        for (int j = 0; j < 4; ++j)
#pragma unroll
            for (int ww = 1; ww < 4; ++ww) { a1[j] += red[0][ww][lane][j]; a2[j] += red[1][ww][lane][j]; }
        ushort4 ys = *(const ushort4*)(Y1 + (size_t)r * H_ + lane * 4);
        a1[0] += sc * bf2f(ys.x); a1[1] += sc * bf2f(ys.y);
        a1[2] += sc * bf2f(ys.z); a1[3] += sc * bf2f(ys.w);
        *(ushort4*)(out1 + (size_t)r * ldo + lane * 4) =
            make_ushort4(f2bf(a1[0]), f2bf(a1[1]), f2bf(a1[2]), f2bf(a1[3]));
        if (Y2) {
            ushort4 ys2 = *(const ushort4*)(Y2 + (size_t)r * H_ + lane * 4);
            a2[0] += sc * bf2f(ys2.x); a2[1] += sc * bf2f(ys2.y);
            a2[2] += sc * bf2f(ys2.z); a2[3] += sc * bf2f(ys2.w);
            *(ushort4*)(out2 + (size_t)r * ldo + lane * 4) =
                make_ushort4(f2bf(a2[0]), f2bf(a2[1]), f2bf(a2[2]), f2bf(a2[3]));
        }
    }
}

// ------------------------------------------------------------ bf16 MFMA GEMM
// C[M,N] = act(A[M,K] @ B[K,N] + bias), A row-major bf16, BT = B^T [N][K] bf16.
// TILE = MF*32 square tile, 4 waves (2x2), wave sub-tile = TILE/2 square.
// LDS tiles [TILE][64] bf16, XOR-swizzled 16B granules (byte ^= (row&7)<<4),
// staged via global_load_lds with pre-swizzled per-lane global source.
// Epilogue: C1 (bf16, +bias, act==1 relu) | act==2 mulv split (C0 mu / C2 softplus)
//           | C0 f32 (+bias).
template<int MF>
__launch_bounds__(256)
__global__ void k_mm(const u16* __restrict__ A, int lda,
                     const u16* __restrict__ BT, int ldbt, int K,
                     float* __restrict__ C0, int ldc0,
                     u16* __restrict__ C1, int ldc1,
                     const float* __restrict__ bias, int act,
                     float* __restrict__ C2) {
    constexpr int TILE = MF * 32;
    __shared__ u16 As[TILE * 64];
    __shared__ u16 Bs[TILE * 64];
    const int tid = threadIdx.x;
    const int lane = tid & 63;
    const int w = tid >> 6;
    const int row0 = blockIdx.y * TILE;
    const int col0 = blockIdx.x * TILE;
    const int wr = (w >> 1) * (TILE / 2);
    const int wc = (w & 1) * (TILE / 2);

    f32x4 acc[MF][MF];
#pragma unroll
    for (int i = 0; i < MF; ++i)
#pragma unroll
        for (int j = 0; j < MF; ++j)
            acc[i][j] = f32x4{0.f, 0.f, 0.f, 0.f};

    int gRow[MF], gCol[MF];
#pragma unroll
    for (int i = 0; i < MF; ++i) {
        int G = (w * MF + i) * 64 + lane;
        int r = G >> 3;
        gRow[i] = r;
        gCol[i] = ((G & 7) ^ (r & 7)) << 3;   // pre-swizzled source element col
    }

    for (int k0 = 0; k0 < K; k0 += 64) {
#pragma unroll
        for (int i = 0; i < MF; ++i) {
            const u16* sa = A + (size_t)(row0 + gRow[i]) * lda + k0 + gCol[i];
            __builtin_amdgcn_global_load_lds(
                (const __attribute__((address_space(1))) void*)sa,
                (__attribute__((address_space(3))) void*)(As + (w * MF + i) * 512), 16, 0, 0);
            const u16* sb = BT + (size_t)(col0 + gRow[i]) * ldbt + k0 + gCol[i];
            __builtin_amdgcn_global_load_lds(
                (const __attribute__((address_space(1))) void*)sb,
                (__attribute__((address_space(3))) void*)(Bs + (w * MF + i) * 512), 16, 0, 0);
        }
        __syncthreads();   // compiler drains vmcnt before barrier
#pragma unroll
        for (int kk = 0; kk < 2; ++kk) {
            short8 a[MF], b[MF];
#pragma unroll
            for (int mf = 0; mf < MF; ++mf) {
                int r = wr + mf * 16 + (lane & 15);
                int off = (r * 128 + kk * 64 + (lane >> 4) * 16) ^ ((r & 7) << 4);
                a[mf] = *(const short8*)((const char*)As + off);
            }
#pragma unroll
            for (int nf = 0; nf < MF; ++nf) {
                int r = wc + nf * 16 + (lane & 15);
                int off = (r * 128 + kk * 64 + (lane >> 4) * 16) ^ ((r & 7) << 4);
                b[nf] = *(const short8*)((const char*)Bs + off);
            }
#pragma unroll
            for (int mf = 0; mf < MF; ++mf)
#pragma unroll
                for (int nf = 0; nf < MF; ++nf)
                    acc[mf][nf] = __builtin_amdgcn_mfma_f32_16x16x32_bf16(
                        a[mf], b[nf], acc[mf][nf], 0, 0, 0);
        }
        __syncthreads();
    }

    const int ci = lane & 15;
    const int ri = (lane >> 4) * 4;
#pragma unroll
    for (int mf = 0; mf < MF; ++mf) {
#pragma unroll
        for (int nf = 0; nf < MF; ++nf) {
            int row = row0 + wr + mf * 16 + ri;
            int col = col0 + wc + nf * 16 + ci;
            if (C1) {
                float bv = bias ? bias[col] : 0.f;
#pragma unroll
                for (int i = 0; i < 4; ++i) {
                    float v = acc[mf][nf][i] + bv;
                    if (act == 1) v = fmaxf(v, 0.f);
                    C1[(size_t)(row + i) * ldc1 + col] = f2bf(v);
                }
            } else if (act == 2) {        // mulv split: col<128 mu, else softplus std
#pragma unroll
                for (int i = 0; i < 4; ++i) {
                    float v = acc[mf][nf][i];
                    if (col < 128) C0[(size_t)(row + i) * 128 + col] = v;
                    else {
                        float s = (v > 20.f) ? v : log1pf(expf(v));
                        C2[(size_t)(row + i) * 128 + (col - 128)] = s;
                    }
                }
            } else {
                float bv = bias ? bias[col] : 0.f;
#pragma unroll
                for (int i = 0; i < 4; ++i)
                    C0[(size_t)(row + i) * ldc0 + col] = acc[mf][nf][i] + bv;
            }
        }
    }
}

// ------------------------------------------------ z = eps*std + mu  (bf16 out)
__global__ void k_z(const float* __restrict__ eps_t, const float* __restrict__ stdv,
                    const float* __restrict__ mu, u16* __restrict__ z) {
    int i = blockIdx.x * 256 + threadIdx.x;
    z[i] = f2bf(eps_t[i] * stdv[i] + mu[i]);
}

// ------------------------------------------------ LSTM elementwise update
__global__ void k_lstm(const float* __restrict__ G, float* __restrict__ h,
                       float* __restrict__ c, u16* __restrict__ h_bf) {
    int idx = blockIdx.x * 256 + threadIdx.x;       // over N*H
    int n = idx >> 8, j = idx & 255;
    const float* g = G + (size_t)n * 1024;
    float gi = 1.f / (1.f + expf(-g[j]));
    float gf = 1.f / (1.f + expf(-g[256 + j]));
    float go = 1.f / (1.f + expf(-g[512 + j]));
    float ct = tanhf(g[768 + j]);
    float ho = h[idx], co = c[idx];
    float cn = gf * ho + gi * ct;   // faithful: F*h_old
    float hn = go * tanhf(co);      // faithful: uses old c
    h[idx] = hn;
    c[idx] = cn;
    h_bf[idx] = f2bf(hn);
}

// ------------------------------------------------ dec dropout mask
__global__ void k_zdrop(const float* __restrict__ du, const u16* __restrict__ z,
                        u16* __restrict__ zd) {
    int i = blockIdx.x * 256 + threadIdx.x;
    zd[i] = (du[i] < 0.5f) ? f2bf(2.f * bf2f(z[i])) : (u16)0;
}

__global__ void k_copy4(const float* __restrict__ src, float* __restrict__ dst) {
    int i = blockIdx.x * 256 + threadIdx.x;
    ((float4*)dst)[i] = ((const float4*)src)[i];
}

// ------------------------------------------------ weight prep (once per call)
// transpose+convert: in f32 [Kd][Nd] -> out bf16 [Nd][Kd]
__global__ void k_wt(const float* __restrict__ in, u16* __restrict__ outp,
                     int Kd, int Nd) {
    int idx = blockIdx.x * 256 + threadIdx.x;
    if (idx >= Kd * Nd) return;
    int j = idx / Kd, k = idx % Kd;
    outp[idx] = f2bf(in[(size_t)k * Nd + j]);
}

// mulvT [256][256]: row j<128 from enc_mu_w^T, j>=128 from enc_lv_w^T
__global__ void k_build_mulv(const float* __restrict__ mu_w, const float* __restrict__ lv_w,
                             u16* __restrict__ outp) {
    int idx = blockIdx.x * 256 + threadIdx.x;      // 256*256
    int j = idx >> 8, k = idx & 255;
    float v = (j < 128) ? mu_w[(size_t)k * ZZ + j] : lv_w[(size_t)k * ZZ + (j - 128)];
    outp[idx] = f2bf(v);
}

// BgT [1024][768]: row jj=(g*256+j); col r: [Wx rows 0-255 | Wh | Wx rows 256-511]^T
__global__ void k_build_gates(const float* __restrict__ wx, const float* __restrict__ wh,
                              u16* __restrict__ outp) {
    int idx = blockIdx.x * 256 + threadIdx.x;      // 1024*768
    int jj = idx / 768, r = idx % 768;
    int g = jj >> 8, j = jj & 255;
    float v;
    if (r < 256)      v = wx[((size_t)g * 512 + r) * 256 + j];
    else if (r < 512) v = wh[((size_t)g * 256 + (r - 256)) * 256 + j];
    else              v = wx[((size_t)g * 512 + (r - 256)) * 256 + j];
    outp[idx] = f2bf(v);
}

// straight f32 -> bf16 convert, 4 at a time
__global__ void k_cvt(const float* __restrict__ in, u16* __restrict__ outp, int n4) {
    int i = blockIdx.x * 256 + threadIdx.x;
    if (i >= n4) return;
    float4 v = ((const float4*)in)[i];
    ((ushort4*)outp)[i] = make_ushort4(f2bf(v.x), f2bf(v.y), f2bf(v.z), f2bf(v.w));
}

// ============================================================================
extern "C" void kernel_launch(void* const* d_in, const int* in_sizes, int n_in,
                              void* d_out_v, int out_size, void* d_ws, size_t ws_size,
                              hipStream_t stream) {
    (void)in_sizes; (void)n_in; (void)out_size;
    const float* x          = (const float*)d_in[0];
    const int*   edges      = (const int*)d_in[1];
    const float* eps        = (const float*)d_in[2];
    const float* drop_u     = (const float*)d_in[3];
    const float* phi_x_w    = (const float*)d_in[4];
    const float* phi_x_b    = (const float*)d_in[5];
    const float* phi_z_w    = (const float*)d_in[6];
    const float* phi_z_b    = (const float*)d_in[7];
    const float* enc_w      = (const float*)d_in[8];
    const float* enc_mu_w   = (const float*)d_in[9];
    const float* enc_lv_w   = (const float*)d_in[10];
    const float* prior_w    = (const float*)d_in[11];
    const float* prior_b    = (const float*)d_in[12];
    const float* prior_mu_w = (const float*)d_in[13];
    const float* prior_mu_b = (const float*)d_in[14];
    const float* gru_wx     = (const float*)d_in[17];
    const float* gru_wh     = (const float*)d_in[18];
    float* out = (float*)d_out_v;

    char* base = (char*)d_ws;
    size_t cur = 0;
    auto carve = [&](size_t bytes) -> void* {
        void* p = base + cur;
        cur += (bytes + 255) & ~(size_t)255;
        return p;
    };
    float* dinv      = (float*)carve(NN * 4);
    int*   degcnt    = (int*)carve(NN * 4);
    int*   row_start = (int*)carve((NN + 1) * 4);
    int*   cursor    = (int*)carve(NN * 4);
    int*   col_idx   = (int*)carve((size_t)EE * 4);
    float* val       = (float*)carve((size_t)EE * 4);
    float* h         = (float*)carve((size_t)NN * H_ * 4);
    float* c         = (float*)carve((size_t)NN * H_ * 4);
    float* enc_std   = (float*)carve((size_t)NN * ZZ * 4);
    float* Gpre      = (float*)carve((size_t)NN * 1024 * 4);
    u16* x_bf        = (u16*)carve((size_t)T_ * NN * XD_ * 2);
    u16* h_bf        = (u16*)carve((size_t)NN * H_ * 2);
    u16* phi         = (u16*)carve((size_t)NN * H_ * 2);
    u16* enc_t       = (u16*)carve((size_t)NN * H_ * 2);
    u16* SEb         = (u16*)carve((size_t)NN * H_ * 2);
    u16* prior_t     = (u16*)carve((size_t)NN * H_ * 2);
    u16* XIN         = (u16*)carve((size_t)NN * 768 * 2);
    u16* zbuf        = (u16*)carve((size_t)NN * ZZ * 2);
    u16* zd          = (u16*)carve((size_t)NN * ZZ * 2);
    u16* phi_x_wT    = (u16*)carve((size_t)XD_ * H_ * 2);
    u16* phi_z_wT    = (u16*)carve((size_t)ZZ * H_ * 2);
    u16* enc_wT      = (u16*)carve((size_t)512 * H_ * 2);
    u16* mulvT       = (u16*)carve((size_t)H_ * H_ * 2);
    u16* prior_wT    = (u16*)carve((size_t)H_ * H_ * 2);
    u16* prior_mu_wT = (u16*)carve((size_t)H_ * ZZ * 2);
    u16* BgT         = (u16*)carve((size_t)1024 * 768 * 2);
    if (cur > ws_size) return;

    const size_t NZ = (size_t)NN * ZZ;
    const size_t HOFF = (size_t)2 * T_ * NZ;
    const size_t DECOFF = HOFF + (size_t)NN * H_;

    // ---- weight prep (every call; deterministic)
    k_cvt<<<(T_ * NN * XD_ / 4 + 255) / 256, 256, 0, stream>>>(x, x_bf, T_ * NN * XD_ / 4);
    k_wt<<<(XD_ * H_ + 255) / 256, 256, 0, stream>>>(phi_x_w, phi_x_wT, XD_, H_);
    k_wt<<<(ZZ * H_ + 255) / 256, 256, 0, stream>>>(phi_z_w, phi_z_wT, ZZ, H_);
    k_wt<<<(512 * H_ + 255) / 256, 256, 0, stream>>>(enc_w, enc_wT, 512, H_);
    k_wt<<<(H_ * H_ + 255) / 256, 256, 0, stream>>>(prior_w, prior_wT, H_, H_);
    k_wt<<<(H_ * ZZ + 255) / 256, 256, 0, stream>>>(prior_mu_w, prior_mu_wT, H_, ZZ);
    k_build_mulv<<<(H_ * H_) / 256, 256, 0, stream>>>(enc_mu_w, enc_lv_w, mulvT);
    k_build_gates<<<(1024 * 768) / 256, 256, 0, stream>>>(gru_wx, gru_wh, BgT);

    hipMemsetAsync(h, 0, (size_t)NN * H_ * 4, stream);
    hipMemsetAsync(c, 0, (size_t)NN * H_ * 4, stream);
    hipMemsetAsync(h_bf, 0, (size_t)NN * H_ * 2, stream);

    for (int t = 0; t < T_; ++t) {
        const int* rows = edges + (size_t)t * 2 * EE;
        const int* cols = rows + EE;

        // ---- per-step normalized adjacency (CSR)
        hipMemsetAsync(degcnt, 0, NN * 4, stream);
        k_deg<<<EE / 256, 256, 0, stream>>>(rows, degcnt);
        k_scan_dinv<<<1, 1024, 0, stream>>>(degcnt, row_start, cursor, dinv);
        k_scatter<<<EE / 256, 256, 0, stream>>>(rows, cols, cursor, dinv, col_idx, val);

        // ---- phi_x = relu(x[t] @ phi_x_w + b)
        k_mm<2><<<dim3(4, 64), 256, 0, stream>>>(x_bf + (size_t)t * NN * XD_, XD_,
            phi_x_wT, XD_, XD_, nullptr, 0, phi, H_, phi_x_b, 1, nullptr);

        // ---- XIN[:,0:256] = S@phi_x ; XIN[:,256:512] = S@h
        k_spmm<<<NN, 256, 0, stream>>>(phi, h_bf, row_start, col_idx, val, dinv,
                                       XIN, XIN + 256, 768);

        // ---- enc_t = relu([SX|SH] @ enc_w)
        k_mm<2><<<dim3(4, 64), 256, 0, stream>>>(XIN, 768, enc_wT, 512, 512,
            nullptr, 0, enc_t, H_, nullptr, 1, nullptr);

        // ---- SE = S@enc_t
        k_spmm<<<NN, 256, 0, stream>>>(enc_t, nullptr, row_start, col_idx, val, dinv,
                                       SEb, nullptr, H_);

        // ---- fused enc_mu (f32 -> out) + enc_std (softplus f32)
        k_mm<2><<<dim3(4, 64), 256, 0, stream>>>(SEb, H_, mulvT, H_, H_,
            out + (size_t)t * NZ, 128, nullptr, 0, nullptr, 2, enc_std);

        // ---- prior_t = relu(h @ prior_w + b) ; prior_mu -> out
        k_mm<2><<<dim3(4, 64), 256, 0, stream>>>(h_bf, H_, prior_wT, H_, H_,
            nullptr, 0, prior_t, H_, prior_b, 1, nullptr);
        k_mm<2><<<dim3(2, 64), 256, 0, stream>>>(prior_t, H_, prior_mu_wT, H_, H_,
            out + (size_t)(T_ + t) * NZ, ZZ, nullptr, 0, prior_mu_b, 0, nullptr);

        // ---- z = eps*std + mu
        k_z<<<NN * ZZ / 256, 256, 0, stream>>>(eps + (size_t)t * NZ, enc_std,
                                               out + (size_t)t * NZ, zbuf);

        // ---- phi_z = relu(z @ phi_z_w + b)  (reuses phi buffer)
        k_mm<2><<<dim3(4, 64), 256, 0, stream>>>(zbuf, ZZ, phi_z_wT, ZZ, ZZ,
            nullptr, 0, phi, H_, phi_z_b, 1, nullptr);

        // ---- XIN[:,512:768] = S@phi_z
        k_spmm<<<NN, 256, 0, stream>>>(phi, nullptr, row_start, col_idx, val, dinv,
                                       XIN + 512, nullptr, 768);

        // ---- gates: Gpre[N,1024] = [SX|SH|SZ] @ BgT^T  (all 4 gates, both sides)
        k_mm<2><<<dim3(16, 64), 256, 0, stream>>>(XIN, 768, BgT, 768, 768,
            Gpre, 1024, nullptr, 0, nullptr, 0, nullptr);

        // ---- LSTM state update
        k_lstm<<<NN * H_ / 256, 256, 0, stream>>>(Gpre, h, c, h_bf);
    }

    // ---- final h -> out
    k_copy4<<<NN * H_ / 1024, 256, 0, stream>>>(h, out + HOFF);

    // ---- dec = z_drop @ z_drop.T at t=T-1 (B^T = zd itself)
    k_zdrop<<<NN * ZZ / 256, 256, 0, stream>>>(drop_u + (size_t)(T_ - 1) * NZ, zbuf, zd);
    k_mm<4><<<dim3(32, 32), 256, 0, stream>>>(zd, ZZ, zd, ZZ, ZZ,
        out + DECOFF, NN, nullptr, 0, nullptr, 0, nullptr);
}

// Round 3
// 689.454 us; speedup vs baseline: 3.3157x; 1.1962x over previous
//
#include <hip/hip_runtime.h>
#include <hip/hip_bf16.h>
#include <math.h>

#define T_  6
#define NN  4096
#define XD_ 64
#define H_  256
#define ZZ  128
#define EE  131072

typedef unsigned short u16;
typedef __attribute__((ext_vector_type(8))) short short8;
typedef __attribute__((ext_vector_type(4))) float f32x4;

__device__ __forceinline__ float bf2f(u16 u) { return __uint_as_float(((unsigned)u) << 16); }
__device__ __forceinline__ u16 f2bf(float f) {
    unsigned x = __float_as_uint(f);
    return (u16)((x + 0x7FFFu + ((x >> 16) & 1u)) >> 16);   // RTNE
}

// ---------------------------------------------------- degree hist (batched t)
__global__ void k_deg(const int* __restrict__ edges, int* __restrict__ degcnt) {
    int t = blockIdx.y;
    int e = blockIdx.x * 256 + threadIdx.x;
    const int* rows = edges + (size_t)t * 2 * EE;
    atomicAdd(&degcnt[t * NN + rows[e]], 1);
}

// ---------------------------------- scan (CSR offsets) + dinv; one block per t
__global__ void k_scan_dinv(const int* __restrict__ degcnt_all,
                            int* __restrict__ row_start_all,
                            int* __restrict__ cursor_all,
                            float* __restrict__ dinv_all) {
    __shared__ int sbuf[1024];
    int tt = blockIdx.x;
    const int* degcnt = degcnt_all + tt * NN;
    int* row_start = row_start_all + tt * (NN + 1);
    int* cursor = cursor_all + tt * NN;
    float* dinv = dinv_all + tt * NN;
    int t = threadIdx.x;
    int b = t * 4;
    int v0 = degcnt[b + 0], v1 = degcnt[b + 1], v2 = degcnt[b + 2], v3 = degcnt[b + 3];
    dinv[b + 0] = rsqrtf((float)(v0 + 1));   // +1: self loop
    dinv[b + 1] = rsqrtf((float)(v1 + 1));
    dinv[b + 2] = rsqrtf((float)(v2 + 1));
    dinv[b + 3] = rsqrtf((float)(v3 + 1));
    int s = v0 + v1 + v2 + v3;
    sbuf[t] = s;
    __syncthreads();
    for (int off = 1; off < 1024; off <<= 1) {
        int x = sbuf[t];
        int y = (t >= off) ? sbuf[t - off] : 0;
        __syncthreads();
        sbuf[t] = x + y;
        __syncthreads();
    }
    int excl = sbuf[t] - s;
    int r0 = excl, r1 = excl + v0, r2 = r1 + v1, r3 = r2 + v2;
    row_start[b + 0] = r0; cursor[b + 0] = r0;
    row_start[b + 1] = r1; cursor[b + 1] = r1;
    row_start[b + 2] = r2; cursor[b + 2] = r2;
    row_start[b + 3] = r3; cursor[b + 3] = r3;
    if (t == 1023) row_start[NN] = r3 + v3;
}

// ------------------------------------------------------ CSR scatter (batched)
__global__ void k_scatter(const int* __restrict__ edges,
                          int* __restrict__ cursor, const float* __restrict__ dinv,
                          int* __restrict__ col_idx, float* __restrict__ val) {
    int t = blockIdx.y;
    int e = blockIdx.x * 256 + threadIdx.x;
    const int* rows = edges + (size_t)t * 2 * EE;
    const int* cols = rows + EE;
    int r = rows[e], cc = cols[e];
    int pos = atomicAdd(&cursor[t * NN + r], 1);
    col_idx[(size_t)t * EE + pos] = cc;
    val[(size_t)t * EE + pos] = dinv[t * NN + r] * dinv[t * NN + cc];
}

// ------------------------------------------------- SpMM (bf16): out = S @ Y
// one block per row (grid.x), optional batch over t (grid.y) with strides.
// 4 waves split the edge list; lane owns 4 of 256 cols.
__global__ void k_spmm(const u16* __restrict__ Y1,
                       const int* __restrict__ row_start_all, const int* __restrict__ col_idx_all,
                       const float* __restrict__ val_all, const float* __restrict__ dinv_all,
                       u16* __restrict__ out1, int ldo,
                       long long sY, long long sO) {
    __shared__ float red[4][64][4];
    int t = blockIdx.y;
    const int* row_start = row_start_all + (size_t)t * (NN + 1);
    const int* col_idx = col_idx_all + (size_t)t * EE;
    const float* val = val_all + (size_t)t * EE;
    const float* dinv = dinv_all + (size_t)t * NN;
    const u16* Y = Y1 + (size_t)t * sY;
    u16* outp = out1 + (size_t)t * sO;

    int lane = threadIdx.x & 63, w = threadIdx.x >> 6;
    int r = blockIdx.x;
    int s0 = row_start[r], s1 = row_start[r + 1];
    int deg = s1 - s0;
    int e0 = s0 + ((deg * w) >> 2);
    int e1 = s0 + ((deg * (w + 1)) >> 2);
    float a1[4] = {0.f, 0.f, 0.f, 0.f};
    for (int base = e0; base < e1; base += 64) {
        int n = e1 - base; if (n > 64) n = 64;
        int cl = 0; float vl = 0.f;
        if (base + lane < e1) { cl = col_idx[base + lane]; vl = val[base + lane]; }
        for (int e = 0; e < n; ++e) {
            int cc = __shfl(cl, e);
            float v = __shfl(vl, e);
            ushort4 y = *(const ushort4*)(Y + (size_t)cc * H_ + lane * 4);
            a1[0] += v * bf2f(y.x); a1[1] += v * bf2f(y.y);
            a1[2] += v * bf2f(y.z); a1[3] += v * bf2f(y.w);
        }
    }
#pragma unroll
    for (int j = 0; j < 4; ++j) red[w][lane][j] = a1[j];
    __syncthreads();
    if (w == 0) {
        float dr = dinv[r], sc = dr * dr;
#pragma unroll
        for (int j = 0; j < 4; ++j)
#pragma unroll
            for (int ww = 1; ww < 4; ++ww) a1[j] += red[ww][lane][j];
        ushort4 ys = *(const ushort4*)(Y + (size_t)r * H_ + lane * 4);
        a1[0] += sc * bf2f(ys.x); a1[1] += sc * bf2f(ys.y);
        a1[2] += sc * bf2f(ys.z); a1[3] += sc * bf2f(ys.w);
        *(ushort4*)(outp + (size_t)r * ldo + lane * 4) =
            make_ushort4(f2bf(a1[0]), f2bf(a1[1]), f2bf(a1[2]), f2bf(a1[3]));
    }
}

// ------------------------------------------------------------ bf16 MFMA GEMM
// C = act(A[M,K] @ B[K,N] + bias); A row-major bf16, BT = B^T [N][K] bf16.
// TILE = MF*32 square tile, 4 waves (2x2). LDS XOR-swizzled (byte ^= (row&7)<<4),
// staged via global_load_lds with pre-swizzled per-lane global source.
// act: 0 -> C0 f32 (+bias) ; 1 -> C1 bf16 relu(+bias)
// act 3 (gates+LSTM, MF=2, N'=1024 col-interleaved j*4+g): C0=h, C2=c, C1=h_bf
// act 4 (mu|std interleaved j*2+s, MF=2): C0=out_mu f32, C2=eps, C1=z bf16
template<int MF>
__launch_bounds__(256)
__global__ void k_mm(const u16* __restrict__ A, int lda,
                     const u16* __restrict__ BT, int ldbt, int K,
                     float* __restrict__ C0, int ldc0,
                     u16* __restrict__ C1, int ldc1,
                     const float* __restrict__ bias, int act,
                     float* __restrict__ C2) {
    constexpr int TILE = MF * 32;
    constexpr int STAGE_B = TILE * 64 * 2 * 2;
    constexpr int EPI_B = (MF == 2) ? 64 * 68 * 4 : 0;
    constexpr int SMEM_B = STAGE_B > EPI_B ? STAGE_B : EPI_B;
    __shared__ alignas(16) char smem[SMEM_B];
    u16* As = (u16*)smem;
    u16* Bs = As + TILE * 64;

    const int tid = threadIdx.x;
    const int lane = tid & 63;
    const int w = tid >> 6;
    const int row0 = blockIdx.y * TILE;
    const int col0 = blockIdx.x * TILE;
    const int wr = (w >> 1) * (TILE / 2);
    const int wc = (w & 1) * (TILE / 2);

    f32x4 acc[MF][MF];
#pragma unroll
    for (int i = 0; i < MF; ++i)
#pragma unroll
        for (int j = 0; j < MF; ++j)
            acc[i][j] = f32x4{0.f, 0.f, 0.f, 0.f};

    int gRow[MF], gCol[MF];
#pragma unroll
    for (int i = 0; i < MF; ++i) {
        int G = (w * MF + i) * 64 + lane;
        int r = G >> 3;
        gRow[i] = r;
        gCol[i] = ((G & 7) ^ (r & 7)) << 3;   // pre-swizzled source element col
    }

    for (int k0 = 0; k0 < K; k0 += 64) {
#pragma unroll
        for (int i = 0; i < MF; ++i) {
            const u16* sa = A + (size_t)(row0 + gRow[i]) * lda + k0 + gCol[i];
            __builtin_amdgcn_global_load_lds(
                (const __attribute__((address_space(1))) void*)sa,
                (__attribute__((address_space(3))) void*)(As + (w * MF + i) * 512), 16, 0, 0);
            const u16* sb = BT + (size_t)(col0 + gRow[i]) * ldbt + k0 + gCol[i];
            __builtin_amdgcn_global_load_lds(
                (const __attribute__((address_space(1))) void*)sb,
                (__attribute__((address_space(3))) void*)(Bs + (w * MF + i) * 512), 16, 0, 0);
        }
        __syncthreads();   // compiler drains vmcnt before barrier
#pragma unroll
        for (int kk = 0; kk < 2; ++kk) {
            short8 a[MF], b[MF];
#pragma unroll
            for (int mf = 0; mf < MF; ++mf) {
                int r = wr + mf * 16 + (lane & 15);
                int off = (r * 128 + kk * 64 + (lane >> 4) * 16) ^ ((r & 7) << 4);
                a[mf] = *(const short8*)((const char*)As + off);
            }
#pragma unroll
            for (int nf = 0; nf < MF; ++nf) {
                int r = wc + nf * 16 + (lane & 15);
                int off = (r * 128 + kk * 64 + (lane >> 4) * 16) ^ ((r & 7) << 4);
                b[nf] = *(const short8*)((const char*)Bs + off);
            }
#pragma unroll
            for (int mf = 0; mf < MF; ++mf)
#pragma unroll
                for (int nf = 0; nf < MF; ++nf)
                    acc[mf][nf] = __builtin_amdgcn_mfma_f32_16x16x32_bf16(
                        a[mf], b[nf], acc[mf][nf], 0, 0, 0);
        }
        __syncthreads();
    }

    const int ci = lane & 15;
    const int ri = (lane >> 4) * 4;

    if constexpr (MF == 2) {
        if (act >= 3) {
            float (*epi)[68] = (float(*)[68])smem;
#pragma unroll
            for (int mf = 0; mf < 2; ++mf)
#pragma unroll
                for (int nf = 0; nf < 2; ++nf)
#pragma unroll
                    for (int i = 0; i < 4; ++i)
                        epi[wr + mf * 16 + ri + i][wc + nf * 16 + ci] = acc[mf][nf][i];
            __syncthreads();
            if (act == 3) {           // gates + LSTM: C0=h, C2=c, C1=h_bf
                float* h = C0; float* c = C2; u16* hbf = C1;
#pragma unroll
                for (int k = 0; k < 4; ++k) {
                    int p = tid + k * 256;
                    int row = p >> 4, jl = p & 15;
                    float4 g4 = *(const float4*)&epi[row][jl * 4];
                    float gi = 1.f / (1.f + expf(-g4.x));
                    float gf = 1.f / (1.f + expf(-g4.y));
                    float go = 1.f / (1.f + expf(-g4.z));
                    float ct = tanhf(g4.w);
                    int idx = (row0 + row) * H_ + (col0 >> 2) + jl;
                    float ho = h[idx], co = c[idx];
                    float cn = gf * ho + gi * ct;   // faithful: F*h_old
                    float hn = go * tanhf(co);      // faithful: uses old c
                    h[idx] = hn;
                    c[idx] = cn;
                    hbf[idx] = f2bf(hn);
                }
            } else {                  // act 4: mu|softplus + z: C0=mu_out, C2=eps, C1=z
                float* muo = C0; const float* eps = C2; u16* zo = C1;
#pragma unroll
                for (int k = 0; k < 8; ++k) {
                    int p = tid + k * 256;
                    int row = p >> 5, jl = p & 31;
                    float mu = epi[row][jl * 2];
                    float sp = epi[row][jl * 2 + 1];
                    float sd = (sp > 20.f) ? sp : log1pf(expf(sp));
                    int idx = (row0 + row) * ZZ + (col0 >> 1) + jl;
                    muo[idx] = mu;
                    zo[idx] = f2bf(eps[idx] * sd + mu);
                }
            }
            return;
        }
    }

#pragma unroll
    for (int mf = 0; mf < MF; ++mf) {
#pragma unroll
        for (int nf = 0; nf < MF; ++nf) {
            int row = row0 + wr + mf * 16 + ri;
            int col = col0 + wc + nf * 16 + ci;
            if (C1) {
                float bv = bias ? bias[col] : 0.f;
#pragma unroll
                for (int i = 0; i < 4; ++i) {
                    float v = acc[mf][nf][i] + bv;
                    if (act == 1) v = fmaxf(v, 0.f);
                    C1[(size_t)(row + i) * ldc1 + col] = f2bf(v);
                }
            } else {
                float bv = bias ? bias[col] : 0.f;
#pragma unroll
                for (int i = 0; i < 4; ++i)
                    C0[(size_t)(row + i) * ldc0 + col] = acc[mf][nf][i] + bv;
            }
        }
    }
}

// ------------------------------------------------ dec dropout mask
__global__ void k_zdrop(const float* __restrict__ du, const u16* __restrict__ z,
                        u16* __restrict__ zd) {
    int i = blockIdx.x * 256 + threadIdx.x;
    zd[i] = (du[i] < 0.5f) ? f2bf(2.f * bf2f(z[i])) : (u16)0;
}

__global__ void k_copy4(const float* __restrict__ src, float* __restrict__ dst) {
    int i = blockIdx.x * 256 + threadIdx.x;
    ((float4*)dst)[i] = ((const float4*)src)[i];
}

// ------------------------------------------------ x f32 -> bf16 convert
__global__ void k_cvt(const float* __restrict__ in, u16* __restrict__ outp, int n4) {
    int i = blockIdx.x * 256 + threadIdx.x;
    if (i >= n4) return;
    float4 v = ((const float4*)in)[i];
    ((ushort4*)outp)[i] = make_ushort4(f2bf(v.x), f2bf(v.y), f2bf(v.z), f2bf(v.w));
}

// ------------------------------------------------ all weight prep in one kernel
// segments: phi_x_wT 16384 | phi_z_wT 32768 | enc_wT 131072 | prior_wT 65536 |
//           prior_mu_wT 32768 | mulvT' 65536 | BgT' 786432   (total 1,130,496)
__global__ void k_prep(const float* __restrict__ phi_x_w, const float* __restrict__ phi_z_w,
                       const float* __restrict__ enc_w, const float* __restrict__ prior_w,
                       const float* __restrict__ prior_mu_w,
                       const float* __restrict__ enc_mu_w, const float* __restrict__ enc_lv_w,
                       const float* __restrict__ gru_wx, const float* __restrict__ gru_wh,
                       u16* __restrict__ phi_x_wT, u16* __restrict__ phi_z_wT,
                       u16* __restrict__ enc_wT, u16* __restrict__ prior_wT,
                       u16* __restrict__ prior_mu_wT, u16* __restrict__ mulvT,
                       u16* __restrict__ BgT) {
    int idx = blockIdx.x * 256 + threadIdx.x;
    if (idx < 16384) {                       // phi_x: [64][256] -> [256][64]
        int j = idx >> 6, k = idx & 63;
        phi_x_wT[idx] = f2bf(phi_x_w[k * 256 + j]);
        return;
    }
    idx -= 16384;
    if (idx < 32768) {                       // phi_z: [128][256] -> [256][128]
        int j = idx >> 7, k = idx & 127;
        phi_z_wT[idx] = f2bf(phi_z_w[k * 256 + j]);
        return;
    }
    idx -= 32768;
    if (idx < 131072) {                      // enc: [512][256] -> [256][512]
        int j = idx >> 9, k = idx & 511;
        enc_wT[idx] = f2bf(enc_w[k * 256 + j]);
        return;
    }
    idx -= 131072;
    if (idx < 65536) {                       // prior: [256][256] -> [256][256]
        int j = idx >> 8, k = idx & 255;
        prior_wT[idx] = f2bf(prior_w[k * 256 + j]);
        return;
    }
    idx -= 65536;
    if (idx < 32768) {                       // prior_mu: [256][128] -> [128][256]
        int j = idx >> 8, k = idx & 255;
        prior_mu_wT[idx] = f2bf(prior_mu_w[k * 128 + j]);
        return;
    }
    idx -= 32768;
    if (idx < 65536) {                       // mulv': col' = j*2+s, [256][256K]
        int cp = idx >> 8, k = idx & 255;
        int j = cp >> 1, s = cp & 1;
        float v = s ? enc_lv_w[k * 128 + j] : enc_mu_w[k * 128 + j];
        mulvT[idx] = f2bf(v);
        return;
    }
    idx -= 65536;
    if (idx < 786432) {                      // gates': col' = j*4+g, K=768
        int cp = idx / 768, k = idx % 768;
        int g = cp & 3, j = cp >> 2;
        float v;
        if (k < 256)      v = gru_wx[((size_t)g * 512 + k) * 256 + j];
        else if (k < 512) v = gru_wh[((size_t)g * 256 + (k - 256)) * 256 + j];
        else              v = gru_wx[((size_t)g * 512 + (k - 256)) * 256 + j];
        BgT[idx] = f2bf(v);
    }
}

// ============================================================================
extern "C" void kernel_launch(void* const* d_in, const int* in_sizes, int n_in,
                              void* d_out_v, int out_size, void* d_ws, size_t ws_size,
                              hipStream_t stream) {
    (void)in_sizes; (void)n_in; (void)out_size;
    const float* x          = (const float*)d_in[0];
    const int*   edges      = (const int*)d_in[1];
    const float* eps        = (const float*)d_in[2];
    const float* drop_u     = (const float*)d_in[3];
    const float* phi_x_w    = (const float*)d_in[4];
    const float* phi_x_b    = (const float*)d_in[5];
    const float* phi_z_w    = (const float*)d_in[6];
    const float* phi_z_b    = (const float*)d_in[7];
    const float* enc_w      = (const float*)d_in[8];
    const float* enc_mu_w   = (const float*)d_in[9];
    const float* enc_lv_w   = (const float*)d_in[10];
    const float* prior_w    = (const float*)d_in[11];
    const float* prior_b    = (const float*)d_in[12];
    const float* prior_mu_w = (const float*)d_in[13];
    const float* prior_mu_b = (const float*)d_in[14];
    const float* gru_wx     = (const float*)d_in[17];
    const float* gru_wh     = (const float*)d_in[18];
    float* out = (float*)d_out_v;

    char* base = (char*)d_ws;
    size_t cur = 0;
    auto carve = [&](size_t bytes) -> void* {
        void* p = base + cur;
        cur += (bytes + 255) & ~(size_t)255;
        return p;
    };
    float* dinv      = (float*)carve((size_t)T_ * NN * 4);
    int*   degcnt    = (int*)carve((size_t)T_ * NN * 4);
    int*   row_start = (int*)carve((size_t)T_ * (NN + 1) * 4);
    int*   cursor    = (int*)carve((size_t)T_ * NN * 4);
    int*   col_idx   = (int*)carve((size_t)T_ * EE * 4);
    float* val       = (float*)carve((size_t)T_ * EE * 4);
    float* h         = (float*)carve((size_t)NN * H_ * 4);
    float* c         = (float*)carve((size_t)NN * H_ * 4);
    u16* x_bf        = (u16*)carve((size_t)T_ * NN * XD_ * 2);
    u16* h_bf        = (u16*)carve((size_t)NN * H_ * 2);
    u16* phi6        = (u16*)carve((size_t)T_ * NN * H_ * 2);
    u16* phi         = (u16*)carve((size_t)NN * H_ * 2);
    u16* enc_t       = (u16*)carve((size_t)NN * H_ * 2);
    u16* SEb         = (u16*)carve((size_t)NN * H_ * 2);
    u16* prior_t     = (u16*)carve((size_t)NN * H_ * 2);
    u16* XIN6        = (u16*)carve((size_t)T_ * NN * 768 * 2);
    u16* zbuf        = (u16*)carve((size_t)NN * ZZ * 2);
    u16* zd          = (u16*)carve((size_t)NN * ZZ * 2);
    u16* phi_x_wT    = (u16*)carve((size_t)XD_ * H_ * 2);
    u16* phi_z_wT    = (u16*)carve((size_t)ZZ * H_ * 2);
    u16* enc_wT      = (u16*)carve((size_t)512 * H_ * 2);
    u16* prior_wT    = (u16*)carve((size_t)H_ * H_ * 2);
    u16* prior_mu_wT = (u16*)carve((size_t)ZZ * H_ * 2);
    u16* mulvT       = (u16*)carve((size_t)H_ * H_ * 2);
    u16* BgT         = (u16*)carve((size_t)1024 * 768 * 2);
    if (cur > ws_size) return;

    const size_t NZ = (size_t)NN * ZZ;
    const size_t HOFF = (size_t)2 * T_ * NZ;
    const size_t DECOFF = HOFF + (size_t)NN * H_;

    // ---- prep: converts + weight transposes (2 dispatches)
    k_cvt<<<(T_ * NN * XD_ / 4 + 255) / 256, 256, 0, stream>>>(x, x_bf, T_ * NN * XD_ / 4);
    k_prep<<<(1130496 + 255) / 256, 256, 0, stream>>>(
        phi_x_w, phi_z_w, enc_w, prior_w, prior_mu_w, enc_mu_w, enc_lv_w,
        gru_wx, gru_wh,
        phi_x_wT, phi_z_wT, enc_wT, prior_wT, prior_mu_wT, mulvT, BgT);

    // ---- all 6 CSRs, batched
    hipMemsetAsync(degcnt, 0, (size_t)T_ * NN * 4, stream);
    k_deg<<<dim3(EE / 256, T_), 256, 0, stream>>>(edges, degcnt);
    k_scan_dinv<<<T_, 1024, 0, stream>>>(degcnt, row_start, cursor, dinv);
    k_scatter<<<dim3(EE / 256, T_), 256, 0, stream>>>(edges, cursor, dinv, col_idx, val);

    // ---- phi_x for all t (M = 24576), then SX_t for all t (batched SpMM)
    k_mm<2><<<dim3(4, (T_ * NN) / 64), 256, 0, stream>>>(x_bf, XD_, phi_x_wT, XD_, XD_,
        nullptr, 0, phi6, H_, phi_x_b, 1, nullptr);
    k_spmm<<<dim3(NN, T_), 256, 0, stream>>>(phi6, row_start, col_idx, val, dinv,
        XIN6, 768, (long long)NN * H_, (long long)NN * 768);

    hipMemsetAsync(h, 0, (size_t)NN * H_ * 4, stream);
    hipMemsetAsync(c, 0, (size_t)NN * H_ * 4, stream);
    hipMemsetAsync(h_bf, 0, (size_t)NN * H_ * 2, stream);

    for (int t = 0; t < T_; ++t) {
        const int* rs_t = row_start + (size_t)t * (NN + 1);
        const int* ci_t = col_idx + (size_t)t * EE;
        const float* vv_t = val + (size_t)t * EE;
        const float* dv_t = dinv + (size_t)t * NN;
        u16* xin_t = XIN6 + (size_t)t * NN * 768;

        // ---- SH = S@h  -> XIN[:,256:512]
        k_spmm<<<dim3(NN, 1), 256, 0, stream>>>(h_bf, rs_t, ci_t, vv_t, dv_t,
                                                xin_t + 256, 768, 0, 0);
        // ---- enc_t = relu([SX|SH] @ enc_w)
        k_mm<2><<<dim3(4, 64), 256, 0, stream>>>(xin_t, 768, enc_wT, 512, 512,
            nullptr, 0, enc_t, H_, nullptr, 1, nullptr);
        // ---- SE = S@enc_t
        k_spmm<<<dim3(NN, 1), 256, 0, stream>>>(enc_t, rs_t, ci_t, vv_t, dv_t,
                                                SEb, H_, 0, 0);
        // ---- fused enc_mu -> out, enc_std=softplus, z=eps*std+mu -> zbuf
        k_mm<2><<<dim3(4, 64), 256, 0, stream>>>(SEb, H_, mulvT, H_, H_,
            out + (size_t)t * NZ, 0, zbuf, 0, nullptr, 4, (float*)(eps + (size_t)t * NZ));
        // ---- prior chain
        k_mm<2><<<dim3(4, 64), 256, 0, stream>>>(h_bf, H_, prior_wT, H_, H_,
            nullptr, 0, prior_t, H_, prior_b, 1, nullptr);
        k_mm<2><<<dim3(2, 64), 256, 0, stream>>>(prior_t, H_, prior_mu_wT, H_, H_,
            out + (size_t)(T_ + t) * NZ, ZZ, nullptr, 0, prior_mu_b, 0, nullptr);
        // ---- phi_z = relu(z @ phi_z_w + b)
        k_mm<2><<<dim3(4, 64), 256, 0, stream>>>(zbuf, ZZ, phi_z_wT, ZZ, ZZ,
            nullptr, 0, phi, H_, phi_z_b, 1, nullptr);
        // ---- SZ = S@phi_z -> XIN[:,512:768]
        k_spmm<<<dim3(NN, 1), 256, 0, stream>>>(phi, rs_t, ci_t, vv_t, dv_t,
                                                xin_t + 512, 768, 0, 0);
        // ---- gates GEMM (interleaved cols) + fused LSTM update
        k_mm<2><<<dim3(16, 64), 256, 0, stream>>>(xin_t, 768, BgT, 768, 768,
            h, 0, h_bf, 0, nullptr, 3, c);
    }

    // ---- final h -> out
    k_copy4<<<NN * H_ / 1024, 256, 0, stream>>>(h, out + HOFF);

    // ---- dec = z_drop @ z_drop.T at t=T-1 (B^T = zd itself)
    k_zdrop<<<NN * ZZ / 256, 256, 0, stream>>>(drop_u + (size_t)(T_ - 1) * NZ, zbuf, zd);
    k_mm<4><<<dim3(32, 32), 256, 0, stream>>>(zd, ZZ, zd, ZZ, ZZ,
        out + DECOFF, NN, nullptr, 0, nullptr, 0, nullptr);
}

// Round 4
// 671.922 us; speedup vs baseline: 3.4022x; 1.0261x over previous
//
#include <hip/hip_runtime.h>
#include <hip/hip_bf16.h>
#include <math.h>

#define T_  6
#define NN  4096
#define XD_ 64
#define H_  256
#define ZZ  128
#define EE  131072

typedef unsigned short u16;
typedef __attribute__((ext_vector_type(8))) short short8;
typedef __attribute__((ext_vector_type(4))) float f32x4;

__device__ __forceinline__ float bf2f(u16 u) { return __uint_as_float(((unsigned)u) << 16); }
__device__ __forceinline__ u16 f2bf(float f) {
    unsigned x = __float_as_uint(f);
    return (u16)((x + 0x7FFFu + ((x >> 16) & 1u)) >> 16);   // RTNE
}

// ---------------------------------------------------- degree hist (batched t)
__global__ void k_deg(const int* __restrict__ edges, int* __restrict__ degcnt) {
    int t = blockIdx.y;
    int e = blockIdx.x * 256 + threadIdx.x;
    const int* rows = edges + (size_t)t * 2 * EE;
    atomicAdd(&degcnt[t * NN + rows[e]], 1);
}

// ---------------------------------- scan (CSR offsets) + dinv; one block per t
__global__ void k_scan_dinv(const int* __restrict__ degcnt_all,
                            int* __restrict__ row_start_all,
                            int* __restrict__ cursor_all,
                            float* __restrict__ dinv_all) {
    __shared__ int sbuf[1024];
    int tt = blockIdx.x;
    const int* degcnt = degcnt_all + tt * NN;
    int* row_start = row_start_all + tt * (NN + 1);
    int* cursor = cursor_all + tt * NN;
    float* dinv = dinv_all + tt * NN;
    int t = threadIdx.x;
    int b = t * 4;
    int v0 = degcnt[b + 0], v1 = degcnt[b + 1], v2 = degcnt[b + 2], v3 = degcnt[b + 3];
    dinv[b + 0] = rsqrtf((float)(v0 + 1));   // +1: self loop
    dinv[b + 1] = rsqrtf((float)(v1 + 1));
    dinv[b + 2] = rsqrtf((float)(v2 + 1));
    dinv[b + 3] = rsqrtf((float)(v3 + 1));
    int s = v0 + v1 + v2 + v3;
    sbuf[t] = s;
    __syncthreads();
    for (int off = 1; off < 1024; off <<= 1) {
        int x = sbuf[t];
        int y = (t >= off) ? sbuf[t - off] : 0;
        __syncthreads();
        sbuf[t] = x + y;
        __syncthreads();
    }
    int excl = sbuf[t] - s;
    int r0 = excl, r1 = excl + v0, r2 = r1 + v1, r3 = r2 + v2;
    row_start[b + 0] = r0; cursor[b + 0] = r0;
    row_start[b + 1] = r1; cursor[b + 1] = r1;
    row_start[b + 2] = r2; cursor[b + 2] = r2;
    row_start[b + 3] = r3; cursor[b + 3] = r3;
    if (t == 1023) row_start[NN] = r3 + v3;
}

// ------------------------------------------------------ CSR scatter (batched)
__global__ void k_scatter(const int* __restrict__ edges,
                          int* __restrict__ cursor, const float* __restrict__ dinv,
                          int* __restrict__ col_idx, float* __restrict__ val) {
    int t = blockIdx.y;
    int e = blockIdx.x * 256 + threadIdx.x;
    const int* rows = edges + (size_t)t * 2 * EE;
    const int* cols = rows + EE;
    int r = rows[e], cc = cols[e];
    int pos = atomicAdd(&cursor[t * NN + r], 1);
    col_idx[(size_t)t * EE + pos] = cc;
    val[(size_t)t * EE + pos] = dinv[t * NN + r] * dinv[t * NN + cc];
}

// ------------------------------------------------- SpMM row body (bf16)
// one block per row; 4 waves split the edge list; lane owns 4 of 256 cols.
__device__ __forceinline__ void sp_row(const u16* __restrict__ Y,
                                       const int* __restrict__ row_start,
                                       const int* __restrict__ col_idx,
                                       const float* __restrict__ val,
                                       const float* __restrict__ dinv,
                                       u16* __restrict__ outp, int ldo,
                                       int r, float (*red)[64][4]) {
    int lane = threadIdx.x & 63, w = threadIdx.x >> 6;
    int s0 = row_start[r], s1 = row_start[r + 1];
    int deg = s1 - s0;
    int e0 = s0 + ((deg * w) >> 2);
    int e1 = s0 + ((deg * (w + 1)) >> 2);
    float a1[4] = {0.f, 0.f, 0.f, 0.f};
    for (int base = e0; base < e1; base += 64) {
        int n = e1 - base; if (n > 64) n = 64;
        int cl = 0; float vl = 0.f;
        if (base + lane < e1) { cl = col_idx[base + lane]; vl = val[base + lane]; }
        for (int e = 0; e < n; ++e) {
            int cc = __shfl(cl, e);
            float v = __shfl(vl, e);
            ushort4 y = *(const ushort4*)(Y + (size_t)cc * H_ + lane * 4);
            a1[0] += v * bf2f(y.x); a1[1] += v * bf2f(y.y);
            a1[2] += v * bf2f(y.z); a1[3] += v * bf2f(y.w);
        }
    }
#pragma unroll
    for (int j = 0; j < 4; ++j) red[w][lane][j] = a1[j];
    __syncthreads();
    if (w == 0) {
        float dr = dinv[r], sc = dr * dr;
#pragma unroll
        for (int j = 0; j < 4; ++j)
#pragma unroll
            for (int ww = 1; ww < 4; ++ww) a1[j] += red[ww][lane][j];
        ushort4 ys = *(const ushort4*)(Y + (size_t)r * H_ + lane * 4);
        a1[0] += sc * bf2f(ys.x); a1[1] += sc * bf2f(ys.y);
        a1[2] += sc * bf2f(ys.z); a1[3] += sc * bf2f(ys.w);
        *(ushort4*)(outp + (size_t)r * ldo + lane * 4) =
            make_ushort4(f2bf(a1[0]), f2bf(a1[1]), f2bf(a1[2]), f2bf(a1[3]));
    }
}

// batched-t SpMM wrapper
__global__ void k_spmm(const u16* __restrict__ Y1,
                       const int* __restrict__ row_start_all, const int* __restrict__ col_idx_all,
                       const float* __restrict__ val_all, const float* __restrict__ dinv_all,
                       u16* __restrict__ out1, int ldo,
                       long long sY, long long sO) {
    __shared__ float red[4][64][4];
    int t = blockIdx.y;
    sp_row(Y1 + (size_t)t * sY, row_start_all + (size_t)t * (NN + 1),
           col_idx_all + (size_t)t * EE, val_all + (size_t)t * EE,
           dinv_all + (size_t)t * NN, out1 + (size_t)t * sO, ldo,
           blockIdx.x, red);
}

// ------------------------------------------------------------ MFMA GEMM core
// A row-major bf16, BT = B^T [N][K] bf16; accumulates TILE x TILE at (row0,col0).
// LDS XOR-swizzled (byte ^= (row&7)<<4); staged via global_load_lds with
// pre-swizzled per-lane global source.
template<int MF>
__device__ __forceinline__ void mm_core(const u16* __restrict__ A, int lda,
                                        const u16* __restrict__ BT, int ldbt, int K,
                                        int row0, int col0,
                                        f32x4 acc[MF][MF], char* smem) {
    constexpr int TILE = MF * 32;
    u16* As = (u16*)smem;
    u16* Bs = As + TILE * 64;
    const int lane = threadIdx.x & 63;
    const int w = threadIdx.x >> 6;
    const int wr = (w >> 1) * (TILE / 2);
    const int wc = (w & 1) * (TILE / 2);

    int gRow[MF], gCol[MF];
#pragma unroll
    for (int i = 0; i < MF; ++i) {
        int G = (w * MF + i) * 64 + lane;
        int r = G >> 3;
        gRow[i] = r;
        gCol[i] = ((G & 7) ^ (r & 7)) << 3;
    }

    for (int k0 = 0; k0 < K; k0 += 64) {
#pragma unroll
        for (int i = 0; i < MF; ++i) {
            const u16* sa = A + (size_t)(row0 + gRow[i]) * lda + k0 + gCol[i];
            __builtin_amdgcn_global_load_lds(
                (const __attribute__((address_space(1))) void*)sa,
                (__attribute__((address_space(3))) void*)(As + (w * MF + i) * 512), 16, 0, 0);
            const u16* sb = BT + (size_t)(col0 + gRow[i]) * ldbt + k0 + gCol[i];
            __builtin_amdgcn_global_load_lds(
                (const __attribute__((address_space(1))) void*)sb,
                (__attribute__((address_space(3))) void*)(Bs + (w * MF + i) * 512), 16, 0, 0);
        }
        __syncthreads();
#pragma unroll
        for (int kk = 0; kk < 2; ++kk) {
            short8 a[MF], b[MF];
#pragma unroll
            for (int mf = 0; mf < MF; ++mf) {
                int r = wr + mf * 16 + (lane & 15);
                int off = (r * 128 + kk * 64 + (lane >> 4) * 16) ^ ((r & 7) << 4);
                a[mf] = *(const short8*)((const char*)As + off);
            }
#pragma unroll
            for (int nf = 0; nf < MF; ++nf) {
                int r = wc + nf * 16 + (lane & 15);
                int off = (r * 128 + kk * 64 + (lane >> 4) * 16) ^ ((r & 7) << 4);
                b[nf] = *(const short8*)((const char*)Bs + off);
            }
#pragma unroll
            for (int mf = 0; mf < MF; ++mf)
#pragma unroll
                for (int nf = 0; nf < MF; ++nf)
                    acc[mf][nf] = __builtin_amdgcn_mfma_f32_16x16x32_bf16(
                        a[mf], b[nf], acc[mf][nf], 0, 0, 0);
        }
        __syncthreads();
    }
}

// ------------------------------------------------------------ generic GEMM
// act: 0 -> C0 f32 (+bias) ; 1 -> C1 bf16 relu(+bias)
// act 4 (mu|std interleaved j*2+s, MF=2): C0=out_mu f32, C2=eps, C1=z bf16;
//        optional du/zdOut: z_drop = (du<0.5) ? 2z : 0
template<int MF>
__launch_bounds__(256)
__global__ void k_mm(const u16* __restrict__ A, int lda,
                     const u16* __restrict__ BT, int ldbt, int K,
                     float* __restrict__ C0, int ldc0,
                     u16* __restrict__ C1, int ldc1,
                     const float* __restrict__ bias, int act,
                     float* __restrict__ C2,
                     const float* __restrict__ du, u16* __restrict__ zdOut) {
    constexpr int TILE = MF * 32;
    constexpr int STAGE_B = TILE * 64 * 2 * 2;
    constexpr int EPI_B = (MF == 2) ? 64 * 68 * 4 : 0;
    constexpr int SMEM_B = STAGE_B > EPI_B ? STAGE_B : EPI_B;
    __shared__ alignas(16) char smem[SMEM_B];

    const int tid = threadIdx.x;
    const int lane = tid & 63;
    const int w = tid >> 6;
    const int row0 = blockIdx.y * TILE;
    const int col0 = blockIdx.x * TILE;
    const int wr = (w >> 1) * (TILE / 2);
    const int wc = (w & 1) * (TILE / 2);

    f32x4 acc[MF][MF];
#pragma unroll
    for (int i = 0; i < MF; ++i)
#pragma unroll
        for (int j = 0; j < MF; ++j)
            acc[i][j] = f32x4{0.f, 0.f, 0.f, 0.f};

    mm_core<MF>(A, lda, BT, ldbt, K, row0, col0, acc, smem);

    const int ci = lane & 15;
    const int ri = (lane >> 4) * 4;

    if constexpr (MF == 2) {
        if (act == 4) {               // mu|softplus + z (+optional zdrop)
            float (*epi)[68] = (float(*)[68])smem;
#pragma unroll
            for (int mf = 0; mf < 2; ++mf)
#pragma unroll
                for (int nf = 0; nf < 2; ++nf)
#pragma unroll
                    for (int i = 0; i < 4; ++i)
                        epi[wr + mf * 16 + ri + i][wc + nf * 16 + ci] = acc[mf][nf][i];
            __syncthreads();
            float* muo = C0; const float* eps = C2; u16* zo = C1;
#pragma unroll
            for (int k = 0; k < 8; ++k) {
                int p = tid + k * 256;
                int row = p >> 5, jl = p & 31;
                float mu = epi[row][jl * 2];
                float sp = epi[row][jl * 2 + 1];
                float sd = (sp > 20.f) ? sp : log1pf(expf(sp));
                int idx = (row0 + row) * ZZ + (col0 >> 1) + jl;
                muo[idx] = mu;
                u16 z16 = f2bf(eps[idx] * sd + mu);
                zo[idx] = z16;
                if (zdOut)
                    zdOut[idx] = (du[idx] < 0.5f) ? f2bf(2.f * bf2f(z16)) : (u16)0;
            }
            return;
        }
    }

#pragma unroll
    for (int mf = 0; mf < MF; ++mf) {
#pragma unroll
        for (int nf = 0; nf < MF; ++nf) {
            int row = row0 + wr + mf * 16 + ri;
            int col = col0 + wc + nf * 16 + ci;
            if (C1) {
                float bv = bias ? bias[col] : 0.f;
#pragma unroll
                for (int i = 0; i < 4; ++i) {
                    float v = acc[mf][nf][i] + bv;
                    if (act == 1) v = fmaxf(v, 0.f);
                    C1[(size_t)(row + i) * ldc1 + col] = f2bf(v);
                }
            } else {
                float bv = bias ? bias[col] : 0.f;
#pragma unroll
                for (int i = 0; i < 4; ++i)
                    C0[(size_t)(row + i) * ldc0 + col] = acc[mf][nf][i] + bv;
            }
        }
    }
}

// --------------------------------------------- dual GEMM (enc || prior_t)
__launch_bounds__(256)
__global__ void k_dual(const u16* __restrict__ A0, int lda0, const u16* __restrict__ BT0,
                       int ldbt0, int K0, u16* __restrict__ C0d, int ldc0d,
                       const float* __restrict__ b0,
                       const u16* __restrict__ A1, int lda1, const u16* __restrict__ BT1,
                       int ldbt1, int K1, u16* __restrict__ C1d, int ldc1d,
                       const float* __restrict__ b1) {
    __shared__ alignas(16) char smem[16384];
    const int z = blockIdx.z;
    const u16* A = z ? A1 : A0;   int lda = z ? lda1 : lda0;
    const u16* BT = z ? BT1 : BT0; int ldbt = z ? ldbt1 : ldbt0;
    int K = z ? K1 : K0;
    u16* C = z ? C1d : C0d;       int ldc = z ? ldc1d : ldc0d;
    const float* bias = z ? b1 : b0;

    const int lane = threadIdx.x & 63;
    const int w = threadIdx.x >> 6;
    const int row0 = blockIdx.y * 64;
    const int col0 = blockIdx.x * 64;
    const int wr = (w >> 1) * 32, wc = (w & 1) * 32;

    f32x4 acc[2][2];
#pragma unroll
    for (int i = 0; i < 2; ++i)
#pragma unroll
        for (int j = 0; j < 2; ++j) acc[i][j] = f32x4{0.f, 0.f, 0.f, 0.f};
    mm_core<2>(A, lda, BT, ldbt, K, row0, col0, acc, smem);

    const int ci = lane & 15, ri = (lane >> 4) * 4;
#pragma unroll
    for (int mf = 0; mf < 2; ++mf)
#pragma unroll
        for (int nf = 0; nf < 2; ++nf) {
            int row = row0 + wr + mf * 16 + ri;
            int col = col0 + wc + nf * 16 + ci;
            float bv = bias ? bias[col] : 0.f;
#pragma unroll
            for (int i = 0; i < 4; ++i)
                C[(size_t)(row + i) * ldc + col] = f2bf(fmaxf(acc[mf][nf][i] + bv, 0.f));
        }
}

// ------------------------------- hybrid: spmm(SE) blocks + prior_mu GEMM blocks
__launch_bounds__(256)
__global__ void k_sp_mm(const u16* __restrict__ Y, const int* __restrict__ row_start,
                        const int* __restrict__ col_idx, const float* __restrict__ val,
                        const float* __restrict__ dinv, u16* __restrict__ spOut,
                        const u16* __restrict__ A, int lda, const u16* __restrict__ BT,
                        int ldbt, int K, float* __restrict__ C0, int ldc0,
                        const float* __restrict__ bias) {
    __shared__ alignas(16) char smem[16384];
    int bid = blockIdx.x;
    if (bid < NN) {
        sp_row(Y, row_start, col_idx, val, dinv, spOut, H_, bid, (float(*)[64][4])smem);
        return;
    }
    int b2 = bid - NN;
    const int row0 = (b2 >> 1) * 64;
    const int col0 = (b2 & 1) * 64;
    const int lane = threadIdx.x & 63;
    const int w = threadIdx.x >> 6;
    const int wr = (w >> 1) * 32, wc = (w & 1) * 32;
    f32x4 acc[2][2];
#pragma unroll
    for (int i = 0; i < 2; ++i)
#pragma unroll
        for (int j = 0; j < 2; ++j) acc[i][j] = f32x4{0.f, 0.f, 0.f, 0.f};
    mm_core<2>(A, lda, BT, ldbt, K, row0, col0, acc, smem);
    const int ci = lane & 15, ri = (lane >> 4) * 4;
#pragma unroll
    for (int mf = 0; mf < 2; ++mf)
#pragma unroll
        for (int nf = 0; nf < 2; ++nf) {
            int row = row0 + wr + mf * 16 + ri;
            int col = col0 + wc + nf * 16 + ci;
            float bv = bias[col];
#pragma unroll
            for (int i = 0; i < 4; ++i)
                C0[(size_t)(row + i) * ldc0 + col] = acc[mf][nf][i] + bv;
        }
}

// --------------------------------------------- gates GEMM + fused LSTM update
// BgT gate-major: row jj = g*256+j, K=768 ([Wx top|Wh|Wx bottom]).
// Block: 64 rows x 64 j (x4 gate planes). Grid (4, 64). Waves 2x2 over (row,j).
// Gates for one (row,j) land in the same lane across 4 plane-fragments ->
// in-register LSTM. skipSH: skip K 256..511 (h==0 at t=0).
__launch_bounds__(256)
__global__ void k_gates(const u16* __restrict__ XIN, const u16* __restrict__ BgT,
                        float* __restrict__ h, float* __restrict__ c,
                        u16* __restrict__ hbf, float* __restrict__ hOut,
                        int skipSH) {
    __shared__ alignas(16) u16 As[64 * 64];       // 8KB
    __shared__ alignas(16) u16 Bs[256 * 64];      // 32KB
    const int tid = threadIdx.x;
    const int lane = tid & 63;
    const int w = tid >> 6;
    const int row0 = blockIdx.y * 64;
    const int j0 = blockIdx.x * 64;
    const int wr = (w >> 1) * 32;                 // warp row-half
    const int wjc = (w & 1) * 32;                 // warp j-half

    f32x4 acc[2][2][4];                           // [m][j][gate]
#pragma unroll
    for (int m = 0; m < 2; ++m)
#pragma unroll
        for (int j = 0; j < 2; ++j)
#pragma unroll
            for (int g = 0; g < 4; ++g) acc[m][j][g] = f32x4{0.f, 0.f, 0.f, 0.f};

    // staging geometry
    int aRow[2], aCol[2];
#pragma unroll
    for (int i = 0; i < 2; ++i) {
        int G = (w * 2 + i) * 64 + lane;
        int r = G >> 3;
        aRow[i] = r;
        aCol[i] = ((G & 7) ^ (r & 7)) << 3;
    }
    int bRow[8], bCol[8];
#pragma unroll
    for (int i = 0; i < 8; ++i) {
        int G = (w * 8 + i) * 64 + lane;
        int r = G >> 3;                           // 0..255: plane g = r>>6, jr = r&63
        bRow[i] = r;
        bCol[i] = ((G & 7) ^ (r & 7)) << 3;
    }

    const int nIter = skipSH ? 8 : 12;
    for (int it = 0; it < nIter; ++it) {
        int k0 = it * 64 + ((skipSH && it >= 4) ? 256 : 0);
#pragma unroll
        for (int i = 0; i < 2; ++i) {
            const u16* sa = XIN + (size_t)(row0 + aRow[i]) * 768 + k0 + aCol[i];
            __builtin_amdgcn_global_load_lds(
                (const __attribute__((address_space(1))) void*)sa,
                (__attribute__((address_space(3))) void*)(As + (w * 2 + i) * 512), 16, 0, 0);
        }
#pragma unroll
        for (int i = 0; i < 8; ++i) {
            int r = bRow[i];
            const u16* sb = BgT + (size_t)((r >> 6) * 256 + j0 + (r & 63)) * 768 + k0 + bCol[i];
            __builtin_amdgcn_global_load_lds(
                (const __attribute__((address_space(1))) void*)sb,
                (__attribute__((address_space(3))) void*)(Bs + (w * 8 + i) * 512), 16, 0, 0);
        }
        __syncthreads();
#pragma unroll
        for (int kk = 0; kk < 2; ++kk) {
            short8 a[2], b[2][4];
#pragma unroll
            for (int m = 0; m < 2; ++m) {
                int r = wr + m * 16 + (lane & 15);
                int off = (r * 128 + kk * 64 + (lane >> 4) * 16) ^ ((r & 7) << 4);
                a[m] = *(const short8*)((const char*)As + off);
            }
#pragma unroll
            for (int j = 0; j < 2; ++j)
#pragma unroll
                for (int g = 0; g < 4; ++g) {
                    int r = g * 64 + wjc + j * 16 + (lane & 15);
                    int off = (r * 128 + kk * 64 + (lane >> 4) * 16) ^ ((r & 7) << 4);
                    b[j][g] = *(const short8*)((const char*)Bs + off);
                }
#pragma unroll
            for (int m = 0; m < 2; ++m)
#pragma unroll
                for (int j = 0; j < 2; ++j)
#pragma unroll
                    for (int g = 0; g < 4; ++g)
                        acc[m][j][g] = __builtin_amdgcn_mfma_f32_16x16x32_bf16(
                            a[m], b[j][g], acc[m][j][g], 0, 0, 0);
        }
        __syncthreads();
    }

    const int ci = lane & 15;
    const int ri = (lane >> 4) * 4;
#pragma unroll
    for (int m = 0; m < 2; ++m)
#pragma unroll
        for (int j = 0; j < 2; ++j) {
            int jcol = j0 + wjc + j * 16 + ci;
#pragma unroll
            for (int i = 0; i < 4; ++i) {
                int row = row0 + wr + m * 16 + ri + i;
                float gi = 1.f / (1.f + expf(-acc[m][j][0][i]));
                float gf = 1.f / (1.f + expf(-acc[m][j][1][i]));
                float go = 1.f / (1.f + expf(-acc[m][j][2][i]));
                float ct = tanhf(acc[m][j][3][i]);
                int idx = row * H_ + jcol;
                float ho = h[idx], co = c[idx];
                float cn = gf * ho + gi * ct;     // faithful: F*h_old
                float hn = go * tanhf(co);        // faithful: uses old c
                h[idx] = hn;
                c[idx] = cn;
                hbf[idx] = f2bf(hn);
                if (hOut) hOut[idx] = hn;
            }
        }
}

// ------------------------------------------------ x f32 -> bf16 convert
__global__ void k_cvt(const float* __restrict__ in, u16* __restrict__ outp, int n4) {
    int i = blockIdx.x * 256 + threadIdx.x;
    if (i >= n4) return;
    float4 v = ((const float4*)in)[i];
    ((ushort4*)outp)[i] = make_ushort4(f2bf(v.x), f2bf(v.y), f2bf(v.z), f2bf(v.w));
}

// ------------------------------------------------ all weight prep in one kernel
// segments: phi_x_wT 16384 | phi_z_wT 32768 | enc_wT 131072 | prior_wT 65536 |
//           prior_mu_wT 32768 | mulvT' 65536 | BgT 786432   (total 1,130,496)
__global__ void k_prep(const float* __restrict__ phi_x_w, const float* __restrict__ phi_z_w,
                       const float* __restrict__ enc_w, const float* __restrict__ prior_w,
                       const float* __restrict__ prior_mu_w,
                       const float* __restrict__ enc_mu_w, const float* __restrict__ enc_lv_w,
                       const float* __restrict__ gru_wx, const float* __restrict__ gru_wh,
                       u16* __restrict__ phi_x_wT, u16* __restrict__ phi_z_wT,
                       u16* __restrict__ enc_wT, u16* __restrict__ prior_wT,
                       u16* __restrict__ prior_mu_wT, u16* __restrict__ mulvT,
                       u16* __restrict__ BgT) {
    int idx = blockIdx.x * 256 + threadIdx.x;
    if (idx < 16384) {                       // phi_x: [64][256] -> [256][64]
        int j = idx >> 6, k = idx & 63;
        phi_x_wT[idx] = f2bf(phi_x_w[k * 256 + j]);
        return;
    }
    idx -= 16384;
    if (idx < 32768) {                       // phi_z: [128][256] -> [256][128]
        int j = idx >> 7, k = idx & 127;
        phi_z_wT[idx] = f2bf(phi_z_w[k * 256 + j]);
        return;
    }
    idx -= 32768;
    if (idx < 131072) {                      // enc: [512][256] -> [256][512]
        int j = idx >> 9, k = idx & 511;
        enc_wT[idx] = f2bf(enc_w[k * 256 + j]);
        return;
    }
    idx -= 131072;
    if (idx < 65536) {                       // prior: [256][256] -> [256][256]
        int j = idx >> 8, k = idx & 255;
        prior_wT[idx] = f2bf(prior_w[k * 256 + j]);
        return;
    }
    idx -= 65536;
    if (idx < 32768) {                       // prior_mu: [256][128] -> [128][256]
        int j = idx >> 8, k = idx & 255;
        prior_mu_wT[idx] = f2bf(prior_mu_w[k * 128 + j]);
        return;
    }
    idx -= 32768;
    if (idx < 65536) {                       // mulv': col' = j*2+s, rows k=256
        int cp = idx >> 8, k = idx & 255;
        int j = cp >> 1, s = cp & 1;
        float v = s ? enc_lv_w[k * 128 + j] : enc_mu_w[k * 128 + j];
        mulvT[idx] = f2bf(v);
        return;
    }
    idx -= 65536;
    if (idx < 786432) {                      // gates, gate-major: row jj=g*256+j, K=768
        int jj = idx / 768, k = idx % 768;
        int g = jj >> 8, j = jj & 255;
        float v;
        if (k < 256)      v = gru_wx[((size_t)g * 512 + k) * 256 + j];
        else if (k < 512) v = gru_wh[((size_t)g * 256 + (k - 256)) * 256 + j];
        else              v = gru_wx[((size_t)g * 512 + (k - 256)) * 256 + j];
        BgT[idx] = f2bf(v);
    }
}

// ============================================================================
extern "C" void kernel_launch(void* const* d_in, const int* in_sizes, int n_in,
                              void* d_out_v, int out_size, void* d_ws, size_t ws_size,
                              hipStream_t stream) {
    (void)in_sizes; (void)n_in; (void)out_size;
    const float* x          = (const float*)d_in[0];
    const int*   edges      = (const int*)d_in[1];
    const float* eps        = (const float*)d_in[2];
    const float* drop_u     = (const float*)d_in[3];
    const float* phi_x_w    = (const float*)d_in[4];
    const float* phi_x_b    = (const float*)d_in[5];
    const float* phi_z_w    = (const float*)d_in[6];
    const float* phi_z_b    = (const float*)d_in[7];
    const float* enc_w      = (const float*)d_in[8];
    const float* enc_mu_w   = (const float*)d_in[9];
    const float* enc_lv_w   = (const float*)d_in[10];
    const float* prior_w    = (const float*)d_in[11];
    const float* prior_b    = (const float*)d_in[12];
    const float* prior_mu_w = (const float*)d_in[13];
    const float* prior_mu_b = (const float*)d_in[14];
    const float* gru_wx     = (const float*)d_in[17];
    const float* gru_wh     = (const float*)d_in[18];
    float* out = (float*)d_out_v;

    char* base = (char*)d_ws;
    size_t cur = 0;
    auto carve = [&](size_t bytes) -> void* {
        void* p = base + cur;
        cur += (bytes + 255) & ~(size_t)255;
        return p;
    };
    // h, c, h_bf contiguous -> single memset
    float* h         = (float*)carve((size_t)NN * H_ * 4);
    float* c         = (float*)carve((size_t)NN * H_ * 4);
    u16* h_bf        = (u16*)carve((size_t)NN * H_ * 2);
    size_t hcz_bytes = cur;
    float* dinv      = (float*)carve((size_t)T_ * NN * 4);
    int*   degcnt    = (int*)carve((size_t)T_ * NN * 4);
    int*   row_start = (int*)carve((size_t)T_ * (NN + 1) * 4);
    int*   cursor    = (int*)carve((size_t)T_ * NN * 4);
    int*   col_idx   = (int*)carve((size_t)T_ * EE * 4);
    float* val       = (float*)carve((size_t)T_ * EE * 4);
    u16* x_bf        = (u16*)carve((size_t)T_ * NN * XD_ * 2);
    u16* phi6        = (u16*)carve((size_t)T_ * NN * H_ * 2);
    u16* phi         = (u16*)carve((size_t)NN * H_ * 2);
    u16* enc_t       = (u16*)carve((size_t)NN * H_ * 2);
    u16* SEb         = (u16*)carve((size_t)NN * H_ * 2);
    u16* prior_t     = (u16*)carve((size_t)NN * H_ * 2);
    u16* XIN6        = (u16*)carve((size_t)T_ * NN * 768 * 2);
    u16* zbuf        = (u16*)carve((size_t)NN * ZZ * 2);
    u16* zd          = (u16*)carve((size_t)NN * ZZ * 2);
    u16* phi_x_wT    = (u16*)carve((size_t)XD_ * H_ * 2);
    u16* phi_z_wT    = (u16*)carve((size_t)ZZ * H_ * 2);
    u16* enc_wT      = (u16*)carve((size_t)512 * H_ * 2);
    u16* prior_wT    = (u16*)carve((size_t)H_ * H_ * 2);
    u16* prior_mu_wT = (u16*)carve((size_t)ZZ * H_ * 2);
    u16* mulvT       = (u16*)carve((size_t)H_ * H_ * 2);
    u16* BgT         = (u16*)carve((size_t)1024 * 768 * 2);
    if (cur > ws_size) return;

    const size_t NZ = (size_t)NN * ZZ;
    const size_t HOFF = (size_t)2 * T_ * NZ;
    const size_t DECOFF = HOFF + (size_t)NN * H_;

    // ---- prep
    k_cvt<<<(T_ * NN * XD_ / 4 + 255) / 256, 256, 0, stream>>>(x, x_bf, T_ * NN * XD_ / 4);
    k_prep<<<(1130496 + 255) / 256, 256, 0, stream>>>(
        phi_x_w, phi_z_w, enc_w, prior_w, prior_mu_w, enc_mu_w, enc_lv_w,
        gru_wx, gru_wh,
        phi_x_wT, phi_z_wT, enc_wT, prior_wT, prior_mu_wT, mulvT, BgT);

    // ---- all 6 CSRs, batched
    hipMemsetAsync(degcnt, 0, (size_t)T_ * NN * 4, stream);
    k_deg<<<dim3(EE / 256, T_), 256, 0, stream>>>(edges, degcnt);
    k_scan_dinv<<<T_, 1024, 0, stream>>>(degcnt, row_start, cursor, dinv);
    k_scatter<<<dim3(EE / 256, T_), 256, 0, stream>>>(edges, cursor, dinv, col_idx, val);

    // ---- phi_x for all t, then SX_t for all t
    k_mm<2><<<dim3(4, (T_ * NN) / 64), 256, 0, stream>>>(x_bf, XD_, phi_x_wT, XD_, XD_,
        nullptr, 0, phi6, H_, phi_x_b, 1, nullptr, nullptr, nullptr);
    k_spmm<<<dim3(NN, T_), 256, 0, stream>>>(phi6, row_start, col_idx, val, dinv,
        XIN6, 768, (long long)NN * H_, (long long)NN * 768);

    hipMemsetAsync(h, 0, hcz_bytes, stream);   // h, c, h_bf

    for (int t = 0; t < T_; ++t) {
        const int* rs_t = row_start + (size_t)t * (NN + 1);
        const int* ci_t = col_idx + (size_t)t * EE;
        const float* vv_t = val + (size_t)t * EE;
        const float* dv_t = dinv + (size_t)t * NN;
        u16* xin_t = XIN6 + (size_t)t * NN * 768;
        int last = (t == T_ - 1);

        // ---- SH = S@h -> XIN[:,256:512]  (h==0 at t=0: skip)
        if (t > 0)
            k_spmm<<<dim3(NN, 1), 256, 0, stream>>>(h_bf, rs_t, ci_t, vv_t, dv_t,
                                                    xin_t + 256, 768, 0, 0);
        // ---- enc_t = relu([SX|SH] @ enc_w)  ||  prior_t = relu(h @ prior_w + b)
        k_dual<<<dim3(4, 64, 2), 256, 0, stream>>>(
            xin_t, 768, enc_wT, 512, (t == 0) ? 256 : 512, enc_t, H_, nullptr,
            h_bf, H_, prior_wT, H_, H_, prior_t, H_, prior_b);
        // ---- SE = S@enc_t  ||  prior_mu -> out
        k_sp_mm<<<NN + 128, 256, 0, stream>>>(enc_t, rs_t, ci_t, vv_t, dv_t, SEb,
            prior_t, H_, prior_mu_wT, H_, H_,
            out + (size_t)(T_ + t) * NZ, ZZ, prior_mu_b);
        // ---- fused enc_mu -> out, z = eps*softplus+mu -> zbuf (+zdrop at last)
        k_mm<2><<<dim3(4, 64), 256, 0, stream>>>(SEb, H_, mulvT, H_, H_,
            out + (size_t)t * NZ, 0, zbuf, 0, nullptr, 4, (float*)(eps + (size_t)t * NZ),
            last ? drop_u + (size_t)t * NZ : nullptr, last ? zd : nullptr);
        // ---- phi_z = relu(z @ phi_z_w + b)
        k_mm<2><<<dim3(4, 64), 256, 0, stream>>>(zbuf, ZZ, phi_z_wT, ZZ, ZZ,
            nullptr, 0, phi, H_, phi_z_b, 1, nullptr, nullptr, nullptr);
        // ---- SZ = S@phi_z -> XIN[:,512:768]
        k_spmm<<<dim3(NN, 1), 256, 0, stream>>>(phi, rs_t, ci_t, vv_t, dv_t,
                                                xin_t + 512, 768, 0, 0);
        // ---- gates + fused LSTM (writes final h f32 at t=T-1)
        k_gates<<<dim3(4, 64), 256, 0, stream>>>(xin_t, BgT, h, c, h_bf,
            last ? out + HOFF : nullptr, t == 0);
    }

    // ---- dec = z_drop @ z_drop.T (B^T = zd itself)
    k_mm<4><<<dim3(32, 32), 256, 0, stream>>>(zd, ZZ, zd, ZZ, ZZ,
        out + DECOFF, NN, nullptr, 0, nullptr, 0, nullptr, nullptr, nullptr);
}

// Round 5
// 613.562 us; speedup vs baseline: 3.7258x; 1.0951x over previous
//
#include <hip/hip_runtime.h>
#include <hip/hip_bf16.h>
#include <math.h>

#define T_  6
#define NN  4096
#define XD_ 64
#define H_  256
#define ZZ  128
#define EE  131072

typedef unsigned short u16;
typedef __attribute__((ext_vector_type(8))) short short8;
typedef __attribute__((ext_vector_type(4))) float f32x4;

__device__ __forceinline__ float bf2f(u16 u) { return __uint_as_float(((unsigned)u) << 16); }
__device__ __forceinline__ u16 f2bf(float f) {
    unsigned x = __float_as_uint(f);
    return (u16)((x + 0x7FFFu + ((x >> 16) & 1u)) >> 16);   // RTNE
}

// ---------------------------------------------------- degree hist (batched t)
__global__ void k_deg(const int* __restrict__ edges, int* __restrict__ degcnt) {
    int t = blockIdx.y;
    int e = blockIdx.x * 256 + threadIdx.x;
    const int* rows = edges + (size_t)t * 2 * EE;
    atomicAdd(&degcnt[t * NN + rows[e]], 1);
}

// ---------------------------------- scan (CSR offsets) + dinv; one block per t
__global__ void k_scan_dinv(const int* __restrict__ degcnt_all,
                            int* __restrict__ row_start_all,
                            int* __restrict__ cursor_all,
                            float* __restrict__ dinv_all) {
    __shared__ int sbuf[1024];
    int tt = blockIdx.x;
    const int* degcnt = degcnt_all + tt * NN;
    int* row_start = row_start_all + tt * (NN + 1);
    int* cursor = cursor_all + tt * NN;
    float* dinv = dinv_all + tt * NN;
    int t = threadIdx.x;
    int b = t * 4;
    int v0 = degcnt[b + 0], v1 = degcnt[b + 1], v2 = degcnt[b + 2], v3 = degcnt[b + 3];
    dinv[b + 0] = rsqrtf((float)(v0 + 1));   // +1: self loop
    dinv[b + 1] = rsqrtf((float)(v1 + 1));
    dinv[b + 2] = rsqrtf((float)(v2 + 1));
    dinv[b + 3] = rsqrtf((float)(v3 + 1));
    int s = v0 + v1 + v2 + v3;
    sbuf[t] = s;
    __syncthreads();
    for (int off = 1; off < 1024; off <<= 1) {
        int x = sbuf[t];
        int y = (t >= off) ? sbuf[t - off] : 0;
        __syncthreads();
        sbuf[t] = x + y;
        __syncthreads();
    }
    int excl = sbuf[t] - s;
    int r0 = excl, r1 = excl + v0, r2 = r1 + v1, r3 = r2 + v2;
    row_start[b + 0] = r0; cursor[b + 0] = r0;
    row_start[b + 1] = r1; cursor[b + 1] = r1;
    row_start[b + 2] = r2; cursor[b + 2] = r2;
    row_start[b + 3] = r3; cursor[b + 3] = r3;
    if (t == 1023) row_start[NN] = r3 + v3;
}

// ------------------------------------------------------ CSR scatter (batched)
__global__ void k_scatter(const int* __restrict__ edges,
                          int* __restrict__ cursor, const float* __restrict__ dinv,
                          int* __restrict__ col_idx, float* __restrict__ val) {
    int t = blockIdx.y;
    int e = blockIdx.x * 256 + threadIdx.x;
    const int* rows = edges + (size_t)t * 2 * EE;
    const int* cols = rows + EE;
    int r = rows[e], cc = cols[e];
    int pos = atomicAdd(&cursor[t * NN + r], 1);
    col_idx[(size_t)t * EE + pos] = cc;
    val[(size_t)t * EE + pos] = dinv[t * NN + r] * dinv[t * NN + cc];
}

// ------------------------------------------------- SpMM row body (bf16)
// one block per row; 4 waves split the edge list; lane owns 4 of 256 cols.
__device__ __forceinline__ void sp_row(const u16* __restrict__ Y,
                                       const int* __restrict__ row_start,
                                       const int* __restrict__ col_idx,
                                       const float* __restrict__ val,
                                       const float* __restrict__ dinv,
                                       u16* __restrict__ outp, int ldo,
                                       int r, float (*red)[64][4]) {
    int lane = threadIdx.x & 63, w = threadIdx.x >> 6;
    int s0 = row_start[r], s1 = row_start[r + 1];
    int deg = s1 - s0;
    int e0 = s0 + ((deg * w) >> 2);
    int e1 = s0 + ((deg * (w + 1)) >> 2);
    float a1[4] = {0.f, 0.f, 0.f, 0.f};
    for (int base = e0; base < e1; base += 64) {
        int n = e1 - base; if (n > 64) n = 64;
        int cl = 0; float vl = 0.f;
        if (base + lane < e1) { cl = col_idx[base + lane]; vl = val[base + lane]; }
        for (int e = 0; e < n; ++e) {
            int cc = __shfl(cl, e);
            float v = __shfl(vl, e);
            ushort4 y = *(const ushort4*)(Y + (size_t)cc * H_ + lane * 4);
            a1[0] += v * bf2f(y.x); a1[1] += v * bf2f(y.y);
            a1[2] += v * bf2f(y.z); a1[3] += v * bf2f(y.w);
        }
    }
#pragma unroll
    for (int j = 0; j < 4; ++j) red[w][lane][j] = a1[j];
    __syncthreads();
    if (w == 0) {
        float dr = dinv[r], sc = dr * dr;
#pragma unroll
        for (int j = 0; j < 4; ++j)
#pragma unroll
            for (int ww = 1; ww < 4; ++ww) a1[j] += red[ww][lane][j];
        ushort4 ys = *(const ushort4*)(Y + (size_t)r * H_ + lane * 4);
        a1[0] += sc * bf2f(ys.x); a1[1] += sc * bf2f(ys.y);
        a1[2] += sc * bf2f(ys.z); a1[3] += sc * bf2f(ys.w);
        *(ushort4*)(outp + (size_t)r * ldo + lane * 4) =
            make_ushort4(f2bf(a1[0]), f2bf(a1[1]), f2bf(a1[2]), f2bf(a1[3]));
    }
}

// batched-t SpMM wrapper
__global__ void k_spmm(const u16* __restrict__ Y1,
                       const int* __restrict__ row_start_all, const int* __restrict__ col_idx_all,
                       const float* __restrict__ val_all, const float* __restrict__ dinv_all,
                       u16* __restrict__ out1, int ldo,
                       long long sY, long long sO) {
    __shared__ float red[4][64][4];
    int t = blockIdx.y;
    sp_row(Y1 + (size_t)t * sY, row_start_all + (size_t)t * (NN + 1),
           col_idx_all + (size_t)t * EE, val_all + (size_t)t * EE,
           dinv_all + (size_t)t * NN, out1 + (size_t)t * sO, ldo,
           blockIdx.x, red);
}

// ------------------------------------------------------------ MFMA GEMM core
// A row-major bf16, BT = B^T [N][K] bf16; accumulates TILE x TILE at (row0,col0).
// LDS XOR-swizzled (byte ^= (row&7)<<4); staged via global_load_lds with
// pre-swizzled per-lane global source.
template<int MF>
__device__ __forceinline__ void mm_core(const u16* __restrict__ A, int lda,
                                        const u16* __restrict__ BT, int ldbt, int K,
                                        int row0, int col0,
                                        f32x4 acc[MF][MF], char* smem) {
    constexpr int TILE = MF * 32;
    u16* As = (u16*)smem;
    u16* Bs = As + TILE * 64;
    const int lane = threadIdx.x & 63;
    const int w = threadIdx.x >> 6;
    const int wr = (w >> 1) * (TILE / 2);
    const int wc = (w & 1) * (TILE / 2);

    int gRow[MF], gCol[MF];
#pragma unroll
    for (int i = 0; i < MF; ++i) {
        int G = (w * MF + i) * 64 + lane;
        int r = G >> 3;
        gRow[i] = r;
        gCol[i] = ((G & 7) ^ (r & 7)) << 3;
    }

    for (int k0 = 0; k0 < K; k0 += 64) {
#pragma unroll
        for (int i = 0; i < MF; ++i) {
            const u16* sa = A + (size_t)(row0 + gRow[i]) * lda + k0 + gCol[i];
            __builtin_amdgcn_global_load_lds(
                (const __attribute__((address_space(1))) void*)sa,
                (__attribute__((address_space(3))) void*)(As + (w * MF + i) * 512), 16, 0, 0);
            const u16* sb = BT + (size_t)(col0 + gRow[i]) * ldbt + k0 + gCol[i];
            __builtin_amdgcn_global_load_lds(
                (const __attribute__((address_space(1))) void*)sb,
                (__attribute__((address_space(3))) void*)(Bs + (w * MF + i) * 512), 16, 0, 0);
        }
        __syncthreads();
#pragma unroll
        for (int kk = 0; kk < 2; ++kk) {
            short8 a[MF], b[MF];
#pragma unroll
            for (int mf = 0; mf < MF; ++mf) {
                int r = wr + mf * 16 + (lane & 15);
                int off = (r * 128 + kk * 64 + (lane >> 4) * 16) ^ ((r & 7) << 4);
                a[mf] = *(const short8*)((const char*)As + off);
            }
#pragma unroll
            for (int nf = 0; nf < MF; ++nf) {
                int r = wc + nf * 16 + (lane & 15);
                int off = (r * 128 + kk * 64 + (lane >> 4) * 16) ^ ((r & 7) << 4);
                b[nf] = *(const short8*)((const char*)Bs + off);
            }
#pragma unroll
            for (int mf = 0; mf < MF; ++mf)
#pragma unroll
                for (int nf = 0; nf < MF; ++nf)
                    acc[mf][nf] = __builtin_amdgcn_mfma_f32_16x16x32_bf16(
                        a[mf], b[nf], acc[mf][nf], 0, 0, 0);
        }
        __syncthreads();
    }
}

// ------------------------------------------------------------ generic GEMM
// act: 0 -> C0 f32 (+bias) ; 1 -> C1 bf16 relu(+bias)
// act 4 (mu|std interleaved j*2+s, MF=2): C0=out_mu f32, C2=eps, C1=z bf16;
//        optional du/zdOut: z_drop = (du<0.5) ? 2z : 0
template<int MF>
__launch_bounds__(256)
__global__ void k_mm(const u16* __restrict__ A, int lda,
                     const u16* __restrict__ BT, int ldbt, int K,
                     float* __restrict__ C0, int ldc0,
                     u16* __restrict__ C1, int ldc1,
                     const float* __restrict__ bias, int act,
                     float* __restrict__ C2,
                     const float* __restrict__ du, u16* __restrict__ zdOut) {
    constexpr int TILE = MF * 32;
    constexpr int STAGE_B = TILE * 64 * 2 * 2;
    constexpr int EPI_B = (MF == 2) ? 64 * 68 * 4 : 0;
    constexpr int SMEM_B = STAGE_B > EPI_B ? STAGE_B : EPI_B;
    __shared__ alignas(16) char smem[SMEM_B];

    const int tid = threadIdx.x;
    const int lane = tid & 63;
    const int w = tid >> 6;
    const int row0 = blockIdx.y * TILE;
    const int col0 = blockIdx.x * TILE;
    const int wr = (w >> 1) * (TILE / 2);
    const int wc = (w & 1) * (TILE / 2);

    f32x4 acc[MF][MF];
#pragma unroll
    for (int i = 0; i < MF; ++i)
#pragma unroll
        for (int j = 0; j < MF; ++j)
            acc[i][j] = f32x4{0.f, 0.f, 0.f, 0.f};

    mm_core<MF>(A, lda, BT, ldbt, K, row0, col0, acc, smem);

    const int ci = lane & 15;
    const int ri = (lane >> 4) * 4;

    if constexpr (MF == 2) {
        if (act == 4) {               // mu|softplus + z (+optional zdrop)
            float (*epi)[68] = (float(*)[68])smem;
#pragma unroll
            for (int mf = 0; mf < 2; ++mf)
#pragma unroll
                for (int nf = 0; nf < 2; ++nf)
#pragma unroll
                    for (int i = 0; i < 4; ++i)
                        epi[wr + mf * 16 + ri + i][wc + nf * 16 + ci] = acc[mf][nf][i];
            __syncthreads();
            float* muo = C0; const float* eps = C2; u16* zo = C1;
#pragma unroll
            for (int k = 0; k < 8; ++k) {
                int p = tid + k * 256;
                int row = p >> 5, jl = p & 31;
                float mu = epi[row][jl * 2];
                float sp = epi[row][jl * 2 + 1];
                float sd = (sp > 20.f) ? sp : log1pf(expf(sp));
                int idx = (row0 + row) * ZZ + (col0 >> 1) + jl;
                muo[idx] = mu;
                u16 z16 = f2bf(eps[idx] * sd + mu);
                zo[idx] = z16;
                if (zdOut)
                    zdOut[idx] = (du[idx] < 0.5f) ? f2bf(2.f * bf2f(z16)) : (u16)0;
            }
            return;
        }
    }

#pragma unroll
    for (int mf = 0; mf < MF; ++mf) {
#pragma unroll
        for (int nf = 0; nf < MF; ++nf) {
            int row = row0 + wr + mf * 16 + ri;
            int col = col0 + wc + nf * 16 + ci;
            if (C1) {
                float bv = bias ? bias[col] : 0.f;
#pragma unroll
                for (int i = 0; i < 4; ++i) {
                    float v = acc[mf][nf][i] + bv;
                    if (act == 1) v = fmaxf(v, 0.f);
                    C1[(size_t)(row + i) * ldc1 + col] = f2bf(v);
                }
            } else {
                float bv = bias ? bias[col] : 0.f;
#pragma unroll
                for (int i = 0; i < 4; ++i)
                    C0[(size_t)(row + i) * ldc0 + col] = acc[mf][nf][i] + bv;
            }
        }
    }
}

// --------------------------------------------- dual GEMM (enc || prior_t)
__launch_bounds__(256)
__global__ void k_dual(const u16* __restrict__ A0, int lda0, const u16* __restrict__ BT0,
                       int ldbt0, int K0, u16* __restrict__ C0d, int ldc0d,
                       const float* __restrict__ b0,
                       const u16* __restrict__ A1, int lda1, const u16* __restrict__ BT1,
                       int ldbt1, int K1, u16* __restrict__ C1d, int ldc1d,
                       const float* __restrict__ b1) {
    __shared__ alignas(16) char smem[16384];
    const int z = blockIdx.z;
    const u16* A = z ? A1 : A0;   int lda = z ? lda1 : lda0;
    const u16* BT = z ? BT1 : BT0; int ldbt = z ? ldbt1 : ldbt0;
    int K = z ? K1 : K0;
    u16* C = z ? C1d : C0d;       int ldc = z ? ldc1d : ldc0d;
    const float* bias = z ? b1 : b0;

    const int lane = threadIdx.x & 63;
    const int w = threadIdx.x >> 6;
    const int row0 = blockIdx.y * 64;
    const int col0 = blockIdx.x * 64;
    const int wr = (w >> 1) * 32, wc = (w & 1) * 32;

    f32x4 acc[2][2];
#pragma unroll
    for (int i = 0; i < 2; ++i)
#pragma unroll
        for (int j = 0; j < 2; ++j) acc[i][j] = f32x4{0.f, 0.f, 0.f, 0.f};
    mm_core<2>(A, lda, BT, ldbt, K, row0, col0, acc, smem);

    const int ci = lane & 15, ri = (lane >> 4) * 4;
#pragma unroll
    for (int mf = 0; mf < 2; ++mf)
#pragma unroll
        for (int nf = 0; nf < 2; ++nf) {
            int row = row0 + wr + mf * 16 + ri;
            int col = col0 + wc + nf * 16 + ci;
            float bv = bias ? bias[col] : 0.f;
#pragma unroll
            for (int i = 0; i < 4; ++i)
                C[(size_t)(row + i) * ldc + col] = f2bf(fmaxf(acc[mf][nf][i] + bv, 0.f));
        }
}

// ------------------------------- hybrid: spmm(SE) blocks + prior_mu GEMM blocks
__launch_bounds__(256)
__global__ void k_sp_mm(const u16* __restrict__ Y, const int* __restrict__ row_start,
                        const int* __restrict__ col_idx, const float* __restrict__ val,
                        const float* __restrict__ dinv, u16* __restrict__ spOut,
                        const u16* __restrict__ A, int lda, const u16* __restrict__ BT,
                        int ldbt, int K, float* __restrict__ C0, int ldc0,
                        const float* __restrict__ bias) {
    __shared__ alignas(16) char smem[16384];
    int bid = blockIdx.x;
    if (bid < NN) {
        sp_row(Y, row_start, col_idx, val, dinv, spOut, H_, bid, (float(*)[64][4])smem);
        return;
    }
    int b2 = bid - NN;
    const int row0 = (b2 >> 1) * 64;
    const int col0 = (b2 & 1) * 64;
    const int lane = threadIdx.x & 63;
    const int w = threadIdx.x >> 6;
    const int wr = (w >> 1) * 32, wc = (w & 1) * 32;
    f32x4 acc[2][2];
#pragma unroll
    for (int i = 0; i < 2; ++i)
#pragma unroll
        for (int j = 0; j < 2; ++j) acc[i][j] = f32x4{0.f, 0.f, 0.f, 0.f};
    mm_core<2>(A, lda, BT, ldbt, K, row0, col0, acc, smem);
    const int ci = lane & 15, ri = (lane >> 4) * 4;
#pragma unroll
    for (int mf = 0; mf < 2; ++mf)
#pragma unroll
        for (int nf = 0; nf < 2; ++nf) {
            int row = row0 + wr + mf * 16 + ri;
            int col = col0 + wc + nf * 16 + ci;
            float bv = bias[col];
#pragma unroll
            for (int i = 0; i < 4; ++i)
                C0[(size_t)(row + i) * ldc0 + col] = acc[mf][nf][i] + bv;
        }
}

// --------------------------------------------- gates GEMM + fused LSTM update
// BgT col-interleaved gate layout: row cp = j*4+g (N'=1024), K=768.
// Standard 64x64 tile, grid (16,64) = 1024 blocks (4 blocks/CU -> 16 waves/CU).
// Epilogue: stage f32 tile in LDS, each thread computes LSTM for 4 (row,j).
// skipSH: skip K 256..511 (h==0 at t=0). hOut: also write f32 h (final step).
__launch_bounds__(256)
__global__ void k_gates(const u16* __restrict__ XIN, const u16* __restrict__ BgT,
                        float* __restrict__ h, float* __restrict__ c,
                        u16* __restrict__ hbf, float* __restrict__ hOut,
                        int skipSH) {
    __shared__ alignas(16) char smem[64 * 68 * 4];   // 17408B >= 16KB staging
    u16* As = (u16*)smem;
    u16* Bs = As + 64 * 64;
    const int tid = threadIdx.x;
    const int lane = tid & 63;
    const int w = tid >> 6;
    const int row0 = blockIdx.y * 64;
    const int col0 = blockIdx.x * 64;
    const int wr = (w >> 1) * 32;
    const int wc = (w & 1) * 32;

    f32x4 acc[2][2];
#pragma unroll
    for (int i = 0; i < 2; ++i)
#pragma unroll
        for (int j = 0; j < 2; ++j) acc[i][j] = f32x4{0.f, 0.f, 0.f, 0.f};

    int gRow[2], gCol[2];
#pragma unroll
    for (int i = 0; i < 2; ++i) {
        int G = (w * 2 + i) * 64 + lane;
        int r = G >> 3;
        gRow[i] = r;
        gCol[i] = ((G & 7) ^ (r & 7)) << 3;
    }

    const int nIter = skipSH ? 8 : 12;
    for (int it = 0; it < nIter; ++it) {
        int k0 = it * 64 + ((skipSH && it >= 4) ? 256 : 0);
#pragma unroll
        for (int i = 0; i < 2; ++i) {
            const u16* sa = XIN + (size_t)(row0 + gRow[i]) * 768 + k0 + gCol[i];
            __builtin_amdgcn_global_load_lds(
                (const __attribute__((address_space(1))) void*)sa,
                (__attribute__((address_space(3))) void*)(As + (w * 2 + i) * 512), 16, 0, 0);
            const u16* sb = BgT + (size_t)(col0 + gRow[i]) * 768 + k0 + gCol[i];
            __builtin_amdgcn_global_load_lds(
                (const __attribute__((address_space(1))) void*)sb,
                (__attribute__((address_space(3))) void*)(Bs + (w * 2 + i) * 512), 16, 0, 0);
        }
        __syncthreads();
#pragma unroll
        for (int kk = 0; kk < 2; ++kk) {
            short8 a[2], b[2];
#pragma unroll
            for (int mf = 0; mf < 2; ++mf) {
                int r = wr + mf * 16 + (lane & 15);
                int off = (r * 128 + kk * 64 + (lane >> 4) * 16) ^ ((r & 7) << 4);
                a[mf] = *(const short8*)((const char*)As + off);
            }
#pragma unroll
            for (int nf = 0; nf < 2; ++nf) {
                int r = wc + nf * 16 + (lane & 15);
                int off = (r * 128 + kk * 64 + (lane >> 4) * 16) ^ ((r & 7) << 4);
                b[nf] = *(const short8*)((const char*)Bs + off);
            }
#pragma unroll
            for (int mf = 0; mf < 2; ++mf)
#pragma unroll
                for (int nf = 0; nf < 2; ++nf)
                    acc[mf][nf] = __builtin_amdgcn_mfma_f32_16x16x32_bf16(
                        a[mf], b[nf], acc[mf][nf], 0, 0, 0);
        }
        __syncthreads();
    }

    // epilogue: LDS transpose, then LSTM per (row, j)
    const int ci = lane & 15;
    const int ri = (lane >> 4) * 4;
    float (*epi)[68] = (float(*)[68])smem;
#pragma unroll
    for (int mf = 0; mf < 2; ++mf)
#pragma unroll
        for (int nf = 0; nf < 2; ++nf)
#pragma unroll
            for (int i = 0; i < 4; ++i)
                epi[wr + mf * 16 + ri + i][wc + nf * 16 + ci] = acc[mf][nf][i];
    __syncthreads();
#pragma unroll
    for (int k = 0; k < 4; ++k) {
        int p = tid + k * 256;
        int row = p >> 4, jl = p & 15;
        float4 g4 = *(const float4*)&epi[row][jl * 4];
        float gi = 1.f / (1.f + expf(-g4.x));
        float gf = 1.f / (1.f + expf(-g4.y));
        float go = 1.f / (1.f + expf(-g4.z));
        float ct = tanhf(g4.w);
        int idx = (row0 + row) * H_ + (col0 >> 2) + jl;
        float ho = h[idx], co = c[idx];
        float cn = gf * ho + gi * ct;     // faithful: F*h_old
        float hn = go * tanhf(co);        // faithful: uses old c
        h[idx] = hn;
        c[idx] = cn;
        hbf[idx] = f2bf(hn);
        if (hOut) hOut[idx] = hn;
    }
}

// ------------------------------------------------ x f32 -> bf16 convert
__global__ void k_cvt(const float* __restrict__ in, u16* __restrict__ outp, int n4) {
    int i = blockIdx.x * 256 + threadIdx.x;
    if (i >= n4) return;
    float4 v = ((const float4*)in)[i];
    ((ushort4*)outp)[i] = make_ushort4(f2bf(v.x), f2bf(v.y), f2bf(v.z), f2bf(v.w));
}

// ------------------------------------------------ all weight prep in one kernel
// segments: phi_x_wT 16384 | phi_z_wT 32768 | enc_wT 131072 | prior_wT 65536 |
//           prior_mu_wT 32768 | mulvT' 65536 | BgT' 786432   (total 1,130,496)
__global__ void k_prep(const float* __restrict__ phi_x_w, const float* __restrict__ phi_z_w,
                       const float* __restrict__ enc_w, const float* __restrict__ prior_w,
                       const float* __restrict__ prior_mu_w,
                       const float* __restrict__ enc_mu_w, const float* __restrict__ enc_lv_w,
                       const float* __restrict__ gru_wx, const float* __restrict__ gru_wh,
                       u16* __restrict__ phi_x_wT, u16* __restrict__ phi_z_wT,
                       u16* __restrict__ enc_wT, u16* __restrict__ prior_wT,
                       u16* __restrict__ prior_mu_wT, u16* __restrict__ mulvT,
                       u16* __restrict__ BgT) {
    int idx = blockIdx.x * 256 + threadIdx.x;
    if (idx < 16384) {                       // phi_x: [64][256] -> [256][64]
        int j = idx >> 6, k = idx & 63;
        phi_x_wT[idx] = f2bf(phi_x_w[k * 256 + j]);
        return;
    }
    idx -= 16384;
    if (idx < 32768) {                       // phi_z: [128][256] -> [256][128]
        int j = idx >> 7, k = idx & 127;
        phi_z_wT[idx] = f2bf(phi_z_w[k * 256 + j]);
        return;
    }
    idx -= 32768;
    if (idx < 131072) {                      // enc: [512][256] -> [256][512]
        int j = idx >> 9, k = idx & 511;
        enc_wT[idx] = f2bf(enc_w[k * 256 + j]);
        return;
    }
    idx -= 131072;
    if (idx < 65536) {                       // prior: [256][256] -> [256][256]
        int j = idx >> 8, k = idx & 255;
        prior_wT[idx] = f2bf(prior_w[k * 256 + j]);
        return;
    }
    idx -= 65536;
    if (idx < 32768) {                       // prior_mu: [256][128] -> [128][256]
        int j = idx >> 8, k = idx & 255;
        prior_mu_wT[idx] = f2bf(prior_mu_w[k * 128 + j]);
        return;
    }
    idx -= 32768;
    if (idx < 65536) {                       // mulv': col' = j*2+s, rows k=256
        int cp = idx >> 8, k = idx & 255;
        int j = cp >> 1, s = cp & 1;
        float v = s ? enc_lv_w[k * 128 + j] : enc_mu_w[k * 128 + j];
        mulvT[idx] = f2bf(v);
        return;
    }
    idx -= 65536;
    if (idx < 786432) {                      // gates interleaved: row cp=j*4+g, K=768
        int cp = idx / 768, k = idx % 768;
        int g = cp & 3, j = cp >> 2;
        float v;
        if (k < 256)      v = gru_wx[((size_t)g * 512 + k) * 256 + j];
        else if (k < 512) v = gru_wh[((size_t)g * 256 + (k - 256)) * 256 + j];
        else              v = gru_wx[((size_t)g * 512 + (k - 256)) * 256 + j];
        BgT[idx] = f2bf(v);
    }
}

// ============================================================================
extern "C" void kernel_launch(void* const* d_in, const int* in_sizes, int n_in,
                              void* d_out_v, int out_size, void* d_ws, size_t ws_size,
                              hipStream_t stream) {
    (void)in_sizes; (void)n_in; (void)out_size;
    const float* x          = (const float*)d_in[0];
    const int*   edges      = (const int*)d_in[1];
    const float* eps        = (const float*)d_in[2];
    const float* drop_u     = (const float*)d_in[3];
    const float* phi_x_w    = (const float*)d_in[4];
    const float* phi_x_b    = (const float*)d_in[5];
    const float* phi_z_w    = (const float*)d_in[6];
    const float* phi_z_b    = (const float*)d_in[7];
    const float* enc_w      = (const float*)d_in[8];
    const float* enc_mu_w   = (const float*)d_in[9];
    const float* enc_lv_w   = (const float*)d_in[10];
    const float* prior_w    = (const float*)d_in[11];
    const float* prior_b    = (const float*)d_in[12];
    const float* prior_mu_w = (const float*)d_in[13];
    const float* prior_mu_b = (const float*)d_in[14];
    const float* gru_wx     = (const float*)d_in[17];
    const float* gru_wh     = (const float*)d_in[18];
    float* out = (float*)d_out_v;

    char* base = (char*)d_ws;
    size_t cur = 0;
    auto carve = [&](size_t bytes) -> void* {
        void* p = base + cur;
        cur += (bytes + 255) & ~(size_t)255;
        return p;
    };
    // h, c, h_bf contiguous -> single memset
    float* h         = (float*)carve((size_t)NN * H_ * 4);
    float* c         = (float*)carve((size_t)NN * H_ * 4);
    u16* h_bf        = (u16*)carve((size_t)NN * H_ * 2);
    size_t hcz_bytes = cur;
    float* dinv      = (float*)carve((size_t)T_ * NN * 4);
    int*   degcnt    = (int*)carve((size_t)T_ * NN * 4);
    int*   row_start = (int*)carve((size_t)T_ * (NN + 1) * 4);
    int*   cursor    = (int*)carve((size_t)T_ * NN * 4);
    int*   col_idx   = (int*)carve((size_t)T_ * EE * 4);
    float* val       = (float*)carve((size_t)T_ * EE * 4);
    u16* x_bf        = (u16*)carve((size_t)T_ * NN * XD_ * 2);
    u16* phi6        = (u16*)carve((size_t)T_ * NN * H_ * 2);
    u16* phi         = (u16*)carve((size_t)NN * H_ * 2);
    u16* enc_t       = (u16*)carve((size_t)NN * H_ * 2);
    u16* SEb         = (u16*)carve((size_t)NN * H_ * 2);
    u16* prior_t     = (u16*)carve((size_t)NN * H_ * 2);
    u16* XIN6        = (u16*)carve((size_t)T_ * NN * 768 * 2);
    u16* zbuf        = (u16*)carve((size_t)NN * ZZ * 2);
    u16* zd          = (u16*)carve((size_t)NN * ZZ * 2);
    u16* phi_x_wT    = (u16*)carve((size_t)XD_ * H_ * 2);
    u16* phi_z_wT    = (u16*)carve((size_t)ZZ * H_ * 2);
    u16* enc_wT      = (u16*)carve((size_t)512 * H_ * 2);
    u16* prior_wT    = (u16*)carve((size_t)H_ * H_ * 2);
    u16* prior_mu_wT = (u16*)carve((size_t)ZZ * H_ * 2);
    u16* mulvT       = (u16*)carve((size_t)H_ * H_ * 2);
    u16* BgT         = (u16*)carve((size_t)1024 * 768 * 2);
    if (cur > ws_size) return;

    const size_t NZ = (size_t)NN * ZZ;
    const size_t HOFF = (size_t)2 * T_ * NZ;
    const size_t DECOFF = HOFF + (size_t)NN * H_;

    // ---- prep
    k_cvt<<<(T_ * NN * XD_ / 4 + 255) / 256, 256, 0, stream>>>(x, x_bf, T_ * NN * XD_ / 4);
    k_prep<<<(1130496 + 255) / 256, 256, 0, stream>>>(
        phi_x_w, phi_z_w, enc_w, prior_w, prior_mu_w, enc_mu_w, enc_lv_w,
        gru_wx, gru_wh,
        phi_x_wT, phi_z_wT, enc_wT, prior_wT, prior_mu_wT, mulvT, BgT);

    // ---- all 6 CSRs, batched
    hipMemsetAsync(degcnt, 0, (size_t)T_ * NN * 4, stream);
    k_deg<<<dim3(EE / 256, T_), 256, 0, stream>>>(edges, degcnt);
    k_scan_dinv<<<T_, 1024, 0, stream>>>(degcnt, row_start, cursor, dinv);
    k_scatter<<<dim3(EE / 256, T_), 256, 0, stream>>>(edges, cursor, dinv, col_idx, val);

    // ---- phi_x for all t, then SX_t for all t
    k_mm<2><<<dim3(4, (T_ * NN) / 64), 256, 0, stream>>>(x_bf, XD_, phi_x_wT, XD_, XD_,
        nullptr, 0, phi6, H_, phi_x_b, 1, nullptr, nullptr, nullptr);
    k_spmm<<<dim3(NN, T_), 256, 0, stream>>>(phi6, row_start, col_idx, val, dinv,
        XIN6, 768, (long long)NN * H_, (long long)NN * 768);

    hipMemsetAsync(h, 0, hcz_bytes, stream);   // h, c, h_bf

    for (int t = 0; t < T_; ++t) {
        const int* rs_t = row_start + (size_t)t * (NN + 1);
        const int* ci_t = col_idx + (size_t)t * EE;
        const float* vv_t = val + (size_t)t * EE;
        const float* dv_t = dinv + (size_t)t * NN;
        u16* xin_t = XIN6 + (size_t)t * NN * 768;
        int last = (t == T_ - 1);

        // ---- SH = S@h -> XIN[:,256:512]  (h==0 at t=0: skip)
        if (t > 0)
            k_spmm<<<dim3(NN, 1), 256, 0, stream>>>(h_bf, rs_t, ci_t, vv_t, dv_t,
                                                    xin_t + 256, 768, 0, 0);
        // ---- enc_t = relu([SX|SH] @ enc_w)  ||  prior_t = relu(h @ prior_w + b)
        k_dual<<<dim3(4, 64, 2), 256, 0, stream>>>(
            xin_t, 768, enc_wT, 512, (t == 0) ? 256 : 512, enc_t, H_, nullptr,
            h_bf, H_, prior_wT, H_, H_, prior_t, H_, prior_b);
        // ---- SE = S@enc_t  ||  prior_mu -> out
        k_sp_mm<<<NN + 128, 256, 0, stream>>>(enc_t, rs_t, ci_t, vv_t, dv_t, SEb,
            prior_t, H_, prior_mu_wT, H_, H_,
            out + (size_t)(T_ + t) * NZ, ZZ, prior_mu_b);
        // ---- fused enc_mu -> out, z = eps*softplus+mu -> zbuf (+zdrop at last)
        k_mm<2><<<dim3(4, 64), 256, 0, stream>>>(SEb, H_, mulvT, H_, H_,
            out + (size_t)t * NZ, 0, zbuf, 0, nullptr, 4, (float*)(eps + (size_t)t * NZ),
            last ? drop_u + (size_t)t * NZ : nullptr, last ? zd : nullptr);
        // ---- phi_z = relu(z @ phi_z_w + b)
        k_mm<2><<<dim3(4, 64), 256, 0, stream>>>(zbuf, ZZ, phi_z_wT, ZZ, ZZ,
            nullptr, 0, phi, H_, phi_z_b, 1, nullptr, nullptr, nullptr);
        // ---- SZ = S@phi_z -> XIN[:,512:768]
        k_spmm<<<dim3(NN, 1), 256, 0, stream>>>(phi, rs_t, ci_t, vv_t, dv_t,
                                                xin_t + 512, 768, 0, 0);
        // ---- gates + fused LSTM (writes final h f32 at t=T-1)
        k_gates<<<dim3(16, 64), 256, 0, stream>>>(xin_t, BgT, h, c, h_bf,
            last ? out + HOFF : nullptr, t == 0);
    }

    // ---- dec = z_drop @ z_drop.T (B^T = zd itself)
    k_mm<4><<<dim3(32, 32), 256, 0, stream>>>(zd, ZZ, zd, ZZ, ZZ,
        out + DECOFF, NN, nullptr, 0, nullptr, 0, nullptr, nullptr, nullptr);
}

// Round 6
// 611.099 us; speedup vs baseline: 3.7409x; 1.0040x over previous
//
#include <hip/hip_runtime.h>
#include <hip/hip_bf16.h>
#include <math.h>

#define T_  6
#define NN  4096
#define XD_ 64
#define H_  256
#define ZZ  128
#define EE  131072

typedef unsigned short u16;
typedef __attribute__((ext_vector_type(8))) short short8;
typedef __attribute__((ext_vector_type(8))) unsigned short u16x8;
typedef __attribute__((ext_vector_type(4))) float f32x4;

__device__ __forceinline__ float bf2f(u16 u) { return __uint_as_float(((unsigned)u) << 16); }
__device__ __forceinline__ u16 f2bf(float f) {
    unsigned x = __float_as_uint(f);
    return (u16)((x + 0x7FFFu + ((x >> 16) & 1u)) >> 16);   // RTNE
}

// ---------------------------------------------------- degree hist (batched t)
__global__ void k_deg(const int* __restrict__ edges, int* __restrict__ degcnt) {
    int t = blockIdx.y;
    int e = blockIdx.x * 256 + threadIdx.x;
    const int* rows = edges + (size_t)t * 2 * EE;
    atomicAdd(&degcnt[t * NN + rows[e]], 1);
}

// ---------------------------------- scan (CSR offsets) + dinv; one block per t
__global__ void k_scan_dinv(const int* __restrict__ degcnt_all,
                            int* __restrict__ row_start_all,
                            int* __restrict__ cursor_all,
                            float* __restrict__ dinv_all) {
    __shared__ int sbuf[1024];
    int tt = blockIdx.x;
    const int* degcnt = degcnt_all + tt * NN;
    int* row_start = row_start_all + tt * (NN + 1);
    int* cursor = cursor_all + tt * NN;
    float* dinv = dinv_all + tt * NN;
    int t = threadIdx.x;
    int b = t * 4;
    int v0 = degcnt[b + 0], v1 = degcnt[b + 1], v2 = degcnt[b + 2], v3 = degcnt[b + 3];
    dinv[b + 0] = rsqrtf((float)(v0 + 1));   // +1: self loop
    dinv[b + 1] = rsqrtf((float)(v1 + 1));
    dinv[b + 2] = rsqrtf((float)(v2 + 1));
    dinv[b + 3] = rsqrtf((float)(v3 + 1));
    int s = v0 + v1 + v2 + v3;
    sbuf[t] = s;
    __syncthreads();
    for (int off = 1; off < 1024; off <<= 1) {
        int x = sbuf[t];
        int y = (t >= off) ? sbuf[t - off] : 0;
        __syncthreads();
        sbuf[t] = x + y;
        __syncthreads();
    }
    int excl = sbuf[t] - s;
    int r0 = excl, r1 = excl + v0, r2 = r1 + v1, r3 = r2 + v2;
    row_start[b + 0] = r0; cursor[b + 0] = r0;
    row_start[b + 1] = r1; cursor[b + 1] = r1;
    row_start[b + 2] = r2; cursor[b + 2] = r2;
    row_start[b + 3] = r3; cursor[b + 3] = r3;
    if (t == 1023) row_start[NN] = r3 + v3;
}

// ------------------------------------------------------ CSR scatter (batched)
__global__ void k_scatter(const int* __restrict__ edges,
                          int* __restrict__ cursor, const float* __restrict__ dinv,
                          int* __restrict__ col_idx, float* __restrict__ val) {
    int t = blockIdx.y;
    int e = blockIdx.x * 256 + threadIdx.x;
    const int* rows = edges + (size_t)t * 2 * EE;
    const int* cols = rows + EE;
    int r = rows[e], cc = cols[e];
    int pos = atomicAdd(&cursor[t * NN + r], 1);
    col_idx[(size_t)t * EE + pos] = cc;
    val[(size_t)t * EE + pos] = dinv[t * NN + r] * dinv[t * NN + cc];
}

// ------------------------------------------------- SpMM row (one wave, bf16)
// 2 edges/iteration: lanes 0-31 edge e, lanes 32-63 edge e+1; 16B/lane gather.
__device__ __forceinline__ void sp_row_wave(const u16* __restrict__ Y,
                                            const int* __restrict__ row_start,
                                            const int* __restrict__ col_idx,
                                            const float* __restrict__ val,
                                            const float* __restrict__ dinv,
                                            u16* __restrict__ outp, int ldo, int r) {
    int lane = threadIdx.x & 63;
    int half = lane >> 5;
    int cg = lane & 31;                // col group: cols cg*8 .. cg*8+7
    int s0 = row_start[r], s1 = row_start[r + 1];
    float a[8] = {0.f, 0.f, 0.f, 0.f, 0.f, 0.f, 0.f, 0.f};
    for (int base = s0; base < s1; base += 64) {
        int n = s1 - base; if (n > 64) n = 64;
        int cl = 0; float vl = 0.f;
        if (base + lane < s1) { cl = col_idx[base + lane]; vl = val[base + lane]; }
        for (int e = 0; e < n; e += 2) {
            int ei = e + half;
            int cc = __shfl(cl, ei);
            float v = (ei < n) ? __shfl(vl, ei) : 0.f;
            u16x8 y = *(const u16x8*)(Y + (size_t)cc * H_ + cg * 8);
#pragma unroll
            for (int j = 0; j < 8; ++j) a[j] += v * bf2f(y[j]);
        }
    }
#pragma unroll
    for (int j = 0; j < 8; ++j) a[j] += __shfl_xor(a[j], 32);
    if (half == 0) {
        float dr = dinv[r], sc = dr * dr;
        u16x8 ys = *(const u16x8*)(Y + (size_t)r * H_ + cg * 8);
        u16x8 o;
#pragma unroll
        for (int j = 0; j < 8; ++j) o[j] = f2bf(a[j] + sc * bf2f(ys[j]));
        *(u16x8*)(outp + (size_t)r * ldo + cg * 8) = o;
    }
}

// batched-t SpMM: 4 rows per block (1 wave each), grid (NN/4, nt)
__global__ void k_spmm(const u16* __restrict__ Y1,
                       const int* __restrict__ row_start_all, const int* __restrict__ col_idx_all,
                       const float* __restrict__ val_all, const float* __restrict__ dinv_all,
                       u16* __restrict__ out1, int ldo,
                       long long sY, long long sO) {
    int t = blockIdx.y;
    int w = threadIdx.x >> 6;
    sp_row_wave(Y1 + (size_t)t * sY, row_start_all + (size_t)t * (NN + 1),
                col_idx_all + (size_t)t * EE, val_all + (size_t)t * EE,
                dinv_all + (size_t)t * NN, out1 + (size_t)t * sO, ldo,
                blockIdx.x * 4 + w);
}

// ------------------------------------------------------------ MFMA GEMM core
// A row-major bf16, BT = B^T [N][K] bf16; accumulates TILE x TILE at (row0,col0).
// LDS XOR-swizzled (byte ^= (row&7)<<4); staged via global_load_lds with
// pre-swizzled per-lane global source.
template<int MF>
__device__ __forceinline__ void mm_core(const u16* __restrict__ A, int lda,
                                        const u16* __restrict__ BT, int ldbt, int K,
                                        int row0, int col0,
                                        f32x4 acc[MF][MF], char* smem) {
    constexpr int TILE = MF * 32;
    u16* As = (u16*)smem;
    u16* Bs = As + TILE * 64;
    const int lane = threadIdx.x & 63;
    const int w = threadIdx.x >> 6;
    const int wr = (w >> 1) * (TILE / 2);
    const int wc = (w & 1) * (TILE / 2);

    int gRow[MF], gCol[MF];
#pragma unroll
    for (int i = 0; i < MF; ++i) {
        int G = (w * MF + i) * 64 + lane;
        int r = G >> 3;
        gRow[i] = r;
        gCol[i] = ((G & 7) ^ (r & 7)) << 3;
    }

    for (int k0 = 0; k0 < K; k0 += 64) {
#pragma unroll
        for (int i = 0; i < MF; ++i) {
            const u16* sa = A + (size_t)(row0 + gRow[i]) * lda + k0 + gCol[i];
            __builtin_amdgcn_global_load_lds(
                (const __attribute__((address_space(1))) void*)sa,
                (__attribute__((address_space(3))) void*)(As + (w * MF + i) * 512), 16, 0, 0);
            const u16* sb = BT + (size_t)(col0 + gRow[i]) * ldbt + k0 + gCol[i];
            __builtin_amdgcn_global_load_lds(
                (const __attribute__((address_space(1))) void*)sb,
                (__attribute__((address_space(3))) void*)(Bs + (w * MF + i) * 512), 16, 0, 0);
        }
        __syncthreads();
#pragma unroll
        for (int kk = 0; kk < 2; ++kk) {
            short8 a[MF], b[MF];
#pragma unroll
            for (int mf = 0; mf < MF; ++mf) {
                int r = wr + mf * 16 + (lane & 15);
                int off = (r * 128 + kk * 64 + (lane >> 4) * 16) ^ ((r & 7) << 4);
                a[mf] = *(const short8*)((const char*)As + off);
            }
#pragma unroll
            for (int nf = 0; nf < MF; ++nf) {
                int r = wc + nf * 16 + (lane & 15);
                int off = (r * 128 + kk * 64 + (lane >> 4) * 16) ^ ((r & 7) << 4);
                b[nf] = *(const short8*)((const char*)Bs + off);
            }
#pragma unroll
            for (int mf = 0; mf < MF; ++mf)
#pragma unroll
                for (int nf = 0; nf < MF; ++nf)
                    acc[mf][nf] = __builtin_amdgcn_mfma_f32_16x16x32_bf16(
                        a[mf], b[nf], acc[mf][nf], 0, 0, 0);
        }
        __syncthreads();
    }
}

// ------------------------------------------------------------ generic GEMM
// act: 0 -> C0 f32 (+bias) ; 1 -> C1 bf16 relu(+bias)
// act 4 (mu|std interleaved j*2+s, MF=2): C0=out_mu f32, C2=eps, C1=z bf16;
//        optional du/zdOut: z_drop = (du<0.5) ? 2z : 0
template<int MF>
__launch_bounds__(256)
__global__ void k_mm(const u16* __restrict__ A, int lda,
                     const u16* __restrict__ BT, int ldbt, int K,
                     float* __restrict__ C0, int ldc0,
                     u16* __restrict__ C1, int ldc1,
                     const float* __restrict__ bias, int act,
                     float* __restrict__ C2,
                     const float* __restrict__ du, u16* __restrict__ zdOut) {
    constexpr int TILE = MF * 32;
    constexpr int STAGE_B = TILE * 64 * 2 * 2;
    constexpr int EPI_B = (MF == 2) ? 64 * 68 * 4 : 0;
    constexpr int SMEM_B = STAGE_B > EPI_B ? STAGE_B : EPI_B;
    __shared__ alignas(16) char smem[SMEM_B];

    const int tid = threadIdx.x;
    const int lane = tid & 63;
    const int w = tid >> 6;
    const int row0 = blockIdx.y * TILE;
    const int col0 = blockIdx.x * TILE;
    const int wr = (w >> 1) * (TILE / 2);
    const int wc = (w & 1) * (TILE / 2);

    f32x4 acc[MF][MF];
#pragma unroll
    for (int i = 0; i < MF; ++i)
#pragma unroll
        for (int j = 0; j < MF; ++j)
            acc[i][j] = f32x4{0.f, 0.f, 0.f, 0.f};

    mm_core<MF>(A, lda, BT, ldbt, K, row0, col0, acc, smem);

    const int ci = lane & 15;
    const int ri = (lane >> 4) * 4;

    if constexpr (MF == 2) {
        if (act == 4) {               // mu|softplus + z (+optional zdrop)
            float (*epi)[68] = (float(*)[68])smem;
#pragma unroll
            for (int mf = 0; mf < 2; ++mf)
#pragma unroll
                for (int nf = 0; nf < 2; ++nf)
#pragma unroll
                    for (int i = 0; i < 4; ++i)
                        epi[wr + mf * 16 + ri + i][wc + nf * 16 + ci] = acc[mf][nf][i];
            __syncthreads();
            float* muo = C0; const float* eps = C2; u16* zo = C1;
#pragma unroll
            for (int k = 0; k < 8; ++k) {
                int p = tid + k * 256;
                int row = p >> 5, jl = p & 31;
                float mu = epi[row][jl * 2];
                float sp = epi[row][jl * 2 + 1];
                float sd = (sp > 20.f) ? sp : log1pf(expf(sp));
                int idx = (row0 + row) * ZZ + (col0 >> 1) + jl;
                muo[idx] = mu;
                u16 z16 = f2bf(eps[idx] * sd + mu);
                zo[idx] = z16;
                if (zdOut)
                    zdOut[idx] = (du[idx] < 0.5f) ? f2bf(2.f * bf2f(z16)) : (u16)0;
            }
            return;
        }
    }

#pragma unroll
    for (int mf = 0; mf < MF; ++mf) {
#pragma unroll
        for (int nf = 0; nf < MF; ++nf) {
            int row = row0 + wr + mf * 16 + ri;
            int col = col0 + wc + nf * 16 + ci;
            if (C1) {
                float bv = bias ? bias[col] : 0.f;
#pragma unroll
                for (int i = 0; i < 4; ++i) {
                    float v = acc[mf][nf][i] + bv;
                    if (act == 1) v = fmaxf(v, 0.f);
                    C1[(size_t)(row + i) * ldc1 + col] = f2bf(v);
                }
            } else {
                float bv = bias ? bias[col] : 0.f;
#pragma unroll
                for (int i = 0; i < 4; ++i)
                    C0[(size_t)(row + i) * ldc0 + col] = acc[mf][nf][i] + bv;
            }
        }
    }
}

// --------------------------- dual GEMM: z=0 enc (bf16 relu), z=1 prior_mu (f32+bias)
__launch_bounds__(256)
__global__ void k_dual(const u16* __restrict__ A0, int lda0, const u16* __restrict__ BT0,
                       int ldbt0, int K0, u16* __restrict__ Cb0, int ldcb0,
                       const u16* __restrict__ A1, int lda1, const u16* __restrict__ BT1,
                       int ldbt1, int K1, float* __restrict__ Cf1, int ldcf1,
                       const float* __restrict__ bias1) {
    __shared__ alignas(16) char smem[16384];
    const int z = blockIdx.z;
    if (z && blockIdx.x >= 2) return;
    const u16* A = z ? A1 : A0;   int lda = z ? lda1 : lda0;
    const u16* BT = z ? BT1 : BT0; int ldbt = z ? ldbt1 : ldbt0;
    int K = z ? K1 : K0;

    const int lane = threadIdx.x & 63;
    const int w = threadIdx.x >> 6;
    const int row0 = blockIdx.y * 64;
    const int col0 = blockIdx.x * 64;
    const int wr = (w >> 1) * 32, wc = (w & 1) * 32;

    f32x4 acc[2][2];
#pragma unroll
    for (int i = 0; i < 2; ++i)
#pragma unroll
        for (int j = 0; j < 2; ++j) acc[i][j] = f32x4{0.f, 0.f, 0.f, 0.f};
    mm_core<2>(A, lda, BT, ldbt, K, row0, col0, acc, smem);

    const int ci = lane & 15, ri = (lane >> 4) * 4;
#pragma unroll
    for (int mf = 0; mf < 2; ++mf)
#pragma unroll
        for (int nf = 0; nf < 2; ++nf) {
            int row = row0 + wr + mf * 16 + ri;
            int col = col0 + wc + nf * 16 + ci;
            if (z == 0) {
#pragma unroll
                for (int i = 0; i < 4; ++i)
                    Cb0[(size_t)(row + i) * ldcb0 + col] = f2bf(fmaxf(acc[mf][nf][i], 0.f));
            } else {
                float bv = bias1[col];
#pragma unroll
                for (int i = 0; i < 4; ++i)
                    Cf1[(size_t)(row + i) * ldcf1 + col] = acc[mf][nf][i] + bv;
            }
        }
}

// ------------------- hybrid: spmm blocks (NN/4) + 64^2 GEMM blocks (bf16 relu or f32)
__launch_bounds__(256)
__global__ void k_sp_mm(const u16* __restrict__ Y, const int* __restrict__ row_start,
                        const int* __restrict__ col_idx, const float* __restrict__ val,
                        const float* __restrict__ dinv, u16* __restrict__ spOut, int spLdo,
                        int doSp,
                        const u16* __restrict__ A, int lda, const u16* __restrict__ BT,
                        int ldbt, int K, float* __restrict__ Cf, int ldcf,
                        u16* __restrict__ Cb, int ldcb,
                        const float* __restrict__ bias, int gx) {
    __shared__ alignas(16) char smem[16384];
    int bid = blockIdx.x;
    if (bid < NN / 4) {
        if (!doSp) return;
        int w = threadIdx.x >> 6;
        sp_row_wave(Y, row_start, col_idx, val, dinv, spOut, spLdo, bid * 4 + w);
        return;
    }
    int b2 = bid - NN / 4;
    const int row0 = (b2 / gx) * 64;
    const int col0 = (b2 % gx) * 64;
    const int lane = threadIdx.x & 63;
    const int w = threadIdx.x >> 6;
    const int wr = (w >> 1) * 32, wc = (w & 1) * 32;
    f32x4 acc[2][2];
#pragma unroll
    for (int i = 0; i < 2; ++i)
#pragma unroll
        for (int j = 0; j < 2; ++j) acc[i][j] = f32x4{0.f, 0.f, 0.f, 0.f};
    mm_core<2>(A, lda, BT, ldbt, K, row0, col0, acc, smem);
    const int ci = lane & 15, ri = (lane >> 4) * 4;
#pragma unroll
    for (int mf = 0; mf < 2; ++mf)
#pragma unroll
        for (int nf = 0; nf < 2; ++nf) {
            int row = row0 + wr + mf * 16 + ri;
            int col = col0 + wc + nf * 16 + ci;
            float bv = bias ? bias[col] : 0.f;
            if (Cb) {
#pragma unroll
                for (int i = 0; i < 4; ++i)
                    Cb[(size_t)(row + i) * ldcb + col] = f2bf(fmaxf(acc[mf][nf][i] + bv, 0.f));
            } else {
#pragma unroll
                for (int i = 0; i < 4; ++i)
                    Cf[(size_t)(row + i) * ldcf + col] = acc[mf][nf][i] + bv;
            }
        }
}

// --------------------------------------------- gates GEMM + fused LSTM update
// BgT col-interleaved gate layout: row cp = j*4+g (N'=1024), K=768.
// Rect tile 128 rows x 64 cols, grid (16,32) = 512 blocks (2/CU, 8 waves/CU).
// Waves 2x2 over (row 2x64, col 2x32); acc[4][2].
// Epilogue: f32 tile in LDS, per-thread LSTM for 8 (row,j).
// skipSH: skip K 256..511 (h==0 at t=0). hOut: also write f32 h (final step).
__launch_bounds__(256)
__global__ void k_gates(const u16* __restrict__ XIN, const u16* __restrict__ BgT,
                        float* __restrict__ h, float* __restrict__ c,
                        u16* __restrict__ hbf, float* __restrict__ hOut,
                        int skipSH) {
    __shared__ alignas(16) char smem[128 * 68 * 4];   // 34816B; staging uses 24KB
    u16* As = (u16*)smem;                 // 128x64 = 16KB
    u16* Bs = As + 128 * 64;              // 64x64 = 8KB
    const int tid = threadIdx.x;
    const int lane = tid & 63;
    const int w = tid >> 6;
    const int row0 = blockIdx.y * 128;
    const int col0 = blockIdx.x * 64;
    const int wrB = (w >> 1) * 64;
    const int wc = (w & 1) * 32;

    f32x4 acc[4][2];
#pragma unroll
    for (int i = 0; i < 4; ++i)
#pragma unroll
        for (int j = 0; j < 2; ++j) acc[i][j] = f32x4{0.f, 0.f, 0.f, 0.f};

    int aRow[4], aCol[4];
#pragma unroll
    for (int i = 0; i < 4; ++i) {
        int G = (w * 4 + i) * 64 + lane;
        int r = G >> 3;
        aRow[i] = r;
        aCol[i] = ((G & 7) ^ (r & 7)) << 3;
    }
    int bRow[2], bCol[2];
#pragma unroll
    for (int i = 0; i < 2; ++i) {
        int G = (w * 2 + i) * 64 + lane;
        int r = G >> 3;
        bRow[i] = r;
        bCol[i] = ((G & 7) ^ (r & 7)) << 3;
    }

    const int nIter = skipSH ? 8 : 12;
    for (int it = 0; it < nIter; ++it) {
        int k0 = it * 64 + ((skipSH && it >= 4) ? 256 : 0);
#pragma unroll
        for (int i = 0; i < 4; ++i) {
            const u16* sa = XIN + (size_t)(row0 + aRow[i]) * 768 + k0 + aCol[i];
            __builtin_amdgcn_global_load_lds(
                (const __attribute__((address_space(1))) void*)sa,
                (__attribute__((address_space(3))) void*)(As + (w * 4 + i) * 512), 16, 0, 0);
        }
#pragma unroll
        for (int i = 0; i < 2; ++i) {
            const u16* sb = BgT + (size_t)(col0 + bRow[i]) * 768 + k0 + bCol[i];
            __builtin_amdgcn_global_load_lds(
                (const __attribute__((address_space(1))) void*)sb,
                (__attribute__((address_space(3))) void*)(Bs + (w * 2 + i) * 512), 16, 0, 0);
        }
        __syncthreads();
#pragma unroll
        for (int kk = 0; kk < 2; ++kk) {
            short8 a[4], b[2];
#pragma unroll
            for (int mf = 0; mf < 4; ++mf) {
                int r = wrB + mf * 16 + (lane & 15);
                int off = (r * 128 + kk * 64 + (lane >> 4) * 16) ^ ((r & 7) << 4);
                a[mf] = *(const short8*)((const char*)As + off);
            }
#pragma unroll
            for (int nf = 0; nf < 2; ++nf) {
                int r = wc + nf * 16 + (lane & 15);
                int off = (r * 128 + kk * 64 + (lane >> 4) * 16) ^ ((r & 7) << 4);
                b[nf] = *(const short8*)((const char*)Bs + off);
            }
#pragma unroll
            for (int mf = 0; mf < 4; ++mf)
#pragma unroll
                for (int nf = 0; nf < 2; ++nf)
                    acc[mf][nf] = __builtin_amdgcn_mfma_f32_16x16x32_bf16(
                        a[mf], b[nf], acc[mf][nf], 0, 0, 0);
        }
        __syncthreads();
    }

    // epilogue: LDS transpose, then LSTM per (row, j)
    const int ci = lane & 15;
    const int ri = (lane >> 4) * 4;
    float (*epi)[68] = (float(*)[68])smem;
#pragma unroll
    for (int mf = 0; mf < 4; ++mf)
#pragma unroll
        for (int nf = 0; nf < 2; ++nf)
#pragma unroll
            for (int i = 0; i < 4; ++i)
                epi[wrB + mf * 16 + ri + i][wc + nf * 16 + ci] = acc[mf][nf][i];
    __syncthreads();
#pragma unroll
    for (int k = 0; k < 8; ++k) {
        int p = tid + k * 256;                 // 2048 = 128 rows x 16 j
        int row = p >> 4, jl = p & 15;
        float4 g4 = *(const float4*)&epi[row][jl * 4];
        float gi = 1.f / (1.f + expf(-g4.x));
        float gf = 1.f / (1.f + expf(-g4.y));
        float go = 1.f / (1.f + expf(-g4.z));
        float ct = tanhf(g4.w);
        int idx = (row0 + row) * H_ + (col0 >> 2) + jl;
        float ho = h[idx], co = c[idx];
        float cn = gf * ho + gi * ct;     // faithful: F*h_old
        float hn = go * tanhf(co);        // faithful: uses old c
        h[idx] = hn;
        c[idx] = cn;
        hbf[idx] = f2bf(hn);
        if (hOut) hOut[idx] = hn;
    }
}

// ------------------------------------------------ x f32 -> bf16 convert
__global__ void k_cvt(const float* __restrict__ in, u16* __restrict__ outp, int n4) {
    int i = blockIdx.x * 256 + threadIdx.x;
    if (i >= n4) return;
    float4 v = ((const float4*)in)[i];
    ((ushort4*)outp)[i] = make_ushort4(f2bf(v.x), f2bf(v.y), f2bf(v.z), f2bf(v.w));
}

// ------------------------------------------------ all weight prep in one kernel
// segments: phi_x_wT 16384 | phi_z_wT 32768 | enc_wT 131072 | prior_wT 65536 |
//           prior_mu_wT 32768 | mulvT' 65536 | BgT' 786432   (total 1,130,496)
__global__ void k_prep(const float* __restrict__ phi_x_w, const float* __restrict__ phi_z_w,
                       const float* __restrict__ enc_w, const float* __restrict__ prior_w,
                       const float* __restrict__ prior_mu_w,
                       const float* __restrict__ enc_mu_w, const float* __restrict__ enc_lv_w,
                       const float* __restrict__ gru_wx, const float* __restrict__ gru_wh,
                       u16* __restrict__ phi_x_wT, u16* __restrict__ phi_z_wT,
                       u16* __restrict__ enc_wT, u16* __restrict__ prior_wT,
                       u16* __restrict__ prior_mu_wT, u16* __restrict__ mulvT,
                       u16* __restrict__ BgT) {
    int idx = blockIdx.x * 256 + threadIdx.x;
    if (idx < 16384) {                       // phi_x: [64][256] -> [256][64]
        int j = idx >> 6, k = idx & 63;
        phi_x_wT[idx] = f2bf(phi_x_w[k * 256 + j]);
        return;
    }
    idx -= 16384;
    if (idx < 32768) {                       // phi_z: [128][256] -> [256][128]
        int j = idx >> 7, k = idx & 127;
        phi_z_wT[idx] = f2bf(phi_z_w[k * 256 + j]);
        return;
    }
    idx -= 32768;
    if (idx < 131072) {                      // enc: [512][256] -> [256][512]
        int j = idx >> 9, k = idx & 511;
        enc_wT[idx] = f2bf(enc_w[k * 256 + j]);
        return;
    }
    idx -= 131072;
    if (idx < 65536) {                       // prior: [256][256] -> [256][256]
        int j = idx >> 8, k = idx & 255;
        prior_wT[idx] = f2bf(prior_w[k * 256 + j]);
        return;
    }
    idx -= 65536;
    if (idx < 32768) {                       // prior_mu: [256][128] -> [128][256]
        int j = idx >> 8, k = idx & 255;
        prior_mu_wT[idx] = f2bf(prior_mu_w[k * 128 + j]);
        return;
    }
    idx -= 32768;
    if (idx < 65536) {                       // mulv': col' = j*2+s, rows k=256
        int cp = idx >> 8, k = idx & 255;
        int j = cp >> 1, s = cp & 1;
        float v = s ? enc_lv_w[k * 128 + j] : enc_mu_w[k * 128 + j];
        mulvT[idx] = f2bf(v);
        return;
    }
    idx -= 65536;
    if (idx < 786432) {                      // gates interleaved: row cp=j*4+g, K=768
        int cp = idx / 768, k = idx % 768;
        int g = cp & 3, j = cp >> 2;
        float v;
        if (k < 256)      v = gru_wx[((size_t)g * 512 + k) * 256 + j];
        else if (k < 512) v = gru_wh[((size_t)g * 256 + (k - 256)) * 256 + j];
        else              v = gru_wx[((size_t)g * 512 + (k - 256)) * 256 + j];
        BgT[idx] = f2bf(v);
    }
}

// ============================================================================
extern "C" void kernel_launch(void* const* d_in, const int* in_sizes, int n_in,
                              void* d_out_v, int out_size, void* d_ws, size_t ws_size,
                              hipStream_t stream) {
    (void)in_sizes; (void)n_in; (void)out_size;
    const float* x          = (const float*)d_in[0];
    const int*   edges      = (const int*)d_in[1];
    const float* eps        = (const float*)d_in[2];
    const float* drop_u     = (const float*)d_in[3];
    const float* phi_x_w    = (const float*)d_in[4];
    const float* phi_x_b    = (const float*)d_in[5];
    const float* phi_z_w    = (const float*)d_in[6];
    const float* phi_z_b    = (const float*)d_in[7];
    const float* enc_w      = (const float*)d_in[8];
    const float* enc_mu_w   = (const float*)d_in[9];
    const float* enc_lv_w   = (const float*)d_in[10];
    const float* prior_w    = (const float*)d_in[11];
    const float* prior_b    = (const float*)d_in[12];
    const float* prior_mu_w = (const float*)d_in[13];
    const float* prior_mu_b = (const float*)d_in[14];
    const float* gru_wx     = (const float*)d_in[17];
    const float* gru_wh     = (const float*)d_in[18];
    float* out = (float*)d_out_v;

    char* base = (char*)d_ws;
    size_t cur = 0;
    auto carve = [&](size_t bytes) -> void* {
        void* p = base + cur;
        cur += (bytes + 255) & ~(size_t)255;
        return p;
    };
    // h, c, h_bf contiguous -> single memset
    float* h         = (float*)carve((size_t)NN * H_ * 4);
    float* c         = (float*)carve((size_t)NN * H_ * 4);
    u16* h_bf        = (u16*)carve((size_t)NN * H_ * 2);
    size_t hcz_bytes = cur;
    float* dinv      = (float*)carve((size_t)T_ * NN * 4);
    int*   degcnt    = (int*)carve((size_t)T_ * NN * 4);
    int*   row_start = (int*)carve((size_t)T_ * (NN + 1) * 4);
    int*   cursor    = (int*)carve((size_t)T_ * NN * 4);
    int*   col_idx   = (int*)carve((size_t)T_ * EE * 4);
    float* val       = (float*)carve((size_t)T_ * EE * 4);
    u16* x_bf        = (u16*)carve((size_t)T_ * NN * XD_ * 2);
    u16* phi6        = (u16*)carve((size_t)T_ * NN * H_ * 2);
    u16* phi         = (u16*)carve((size_t)NN * H_ * 2);
    u16* enc_t       = (u16*)carve((size_t)NN * H_ * 2);
    u16* SEb         = (u16*)carve((size_t)NN * H_ * 2);
    u16* prior_t     = (u16*)carve((size_t)NN * H_ * 2);
    u16* XIN6        = (u16*)carve((size_t)T_ * NN * 768 * 2);
    u16* zbuf        = (u16*)carve((size_t)NN * ZZ * 2);
    u16* zd          = (u16*)carve((size_t)NN * ZZ * 2);
    u16* phi_x_wT    = (u16*)carve((size_t)XD_ * H_ * 2);
    u16* phi_z_wT    = (u16*)carve((size_t)ZZ * H_ * 2);
    u16* enc_wT      = (u16*)carve((size_t)512 * H_ * 2);
    u16* prior_wT    = (u16*)carve((size_t)H_ * H_ * 2);
    u16* prior_mu_wT = (u16*)carve((size_t)ZZ * H_ * 2);
    u16* mulvT       = (u16*)carve((size_t)H_ * H_ * 2);
    u16* BgT         = (u16*)carve((size_t)1024 * 768 * 2);
    if (cur > ws_size) return;

    const size_t NZ = (size_t)NN * ZZ;
    const size_t HOFF = (size_t)2 * T_ * NZ;
    const size_t DECOFF = HOFF + (size_t)NN * H_;

    // ---- prep
    k_cvt<<<(T_ * NN * XD_ / 4 + 255) / 256, 256, 0, stream>>>(x, x_bf, T_ * NN * XD_ / 4);
    k_prep<<<(1130496 + 255) / 256, 256, 0, stream>>>(
        phi_x_w, phi_z_w, enc_w, prior_w, prior_mu_w, enc_mu_w, enc_lv_w,
        gru_wx, gru_wh,
        phi_x_wT, phi_z_wT, enc_wT, prior_wT, prior_mu_wT, mulvT, BgT);

    // ---- all 6 CSRs, batched
    hipMemsetAsync(degcnt, 0, (size_t)T_ * NN * 4, stream);
    k_deg<<<dim3(EE / 256, T_), 256, 0, stream>>>(edges, degcnt);
    k_scan_dinv<<<T_, 1024, 0, stream>>>(degcnt, row_start, cursor, dinv);
    k_scatter<<<dim3(EE / 256, T_), 256, 0, stream>>>(edges, cursor, dinv, col_idx, val);

    // ---- phi_x for all t, then SX_t for all t
    k_mm<2><<<dim3(4, (T_ * NN) / 64), 256, 0, stream>>>(x_bf, XD_, phi_x_wT, XD_, XD_,
        nullptr, 0, phi6, H_, phi_x_b, 1, nullptr, nullptr, nullptr);
    k_spmm<<<dim3(NN / 4, T_), 256, 0, stream>>>(phi6, row_start, col_idx, val, dinv,
        XIN6, 768, (long long)NN * H_, (long long)NN * 768);

    hipMemsetAsync(h, 0, hcz_bytes, stream);   // h, c, h_bf

    for (int t = 0; t < T_; ++t) {
        const int* rs_t = row_start + (size_t)t * (NN + 1);
        const int* ci_t = col_idx + (size_t)t * EE;
        const float* vv_t = val + (size_t)t * EE;
        const float* dv_t = dinv + (size_t)t * NN;
        u16* xin_t = XIN6 + (size_t)t * NN * 768;
        int last = (t == T_ - 1);

        // ---- P1: SH = S@h -> XIN[:,256:512] (skip at t=0)  ||  prior_t GEMM
        k_sp_mm<<<NN / 4 + 256, 256, 0, stream>>>(h_bf, rs_t, ci_t, vv_t, dv_t,
            xin_t + 256, 768, t > 0,
            h_bf, H_, prior_wT, H_, H_, nullptr, 0, prior_t, H_, prior_b, 4);
        // ---- P2: enc_t = relu([SX|SH] @ enc_w)  ||  prior_mu -> out
        k_dual<<<dim3(4, 64, 2), 256, 0, stream>>>(
            xin_t, 768, enc_wT, 512, (t == 0) ? 256 : 512, enc_t, H_,
            prior_t, H_, prior_mu_wT, H_, H_,
            out + (size_t)(T_ + t) * NZ, ZZ, prior_mu_b);
        // ---- P3: SE = S@enc_t
        k_spmm<<<dim3(NN / 4, 1), 256, 0, stream>>>(enc_t, rs_t, ci_t, vv_t, dv_t,
                                                    SEb, H_, 0, 0);
        // ---- P4: fused enc_mu -> out, z = eps*softplus+mu -> zbuf (+zdrop at last)
        k_mm<2><<<dim3(4, 64), 256, 0, stream>>>(SEb, H_, mulvT, H_, H_,
            out + (size_t)t * NZ, 0, zbuf, 0, nullptr, 4, (float*)(eps + (size_t)t * NZ),
            last ? drop_u + (size_t)t * NZ : nullptr, last ? zd : nullptr);
        // ---- P5: phi_z = relu(z @ phi_z_w + b)
        k_mm<2><<<dim3(4, 64), 256, 0, stream>>>(zbuf, ZZ, phi_z_wT, ZZ, ZZ,
            nullptr, 0, phi, H_, phi_z_b, 1, nullptr, nullptr, nullptr);
        // ---- P6: SZ = S@phi_z -> XIN[:,512:768]
        k_spmm<<<dim3(NN / 4, 1), 256, 0, stream>>>(phi, rs_t, ci_t, vv_t, dv_t,
                                                    xin_t + 512, 768, 0, 0);
        // ---- P7: gates + fused LSTM (writes final h f32 at t=T-1)
        k_gates<<<dim3(16, 32), 256, 0, stream>>>(xin_t, BgT, h, c, h_bf,
            last ? out + HOFF : nullptr, t == 0);
    }

    // ---- dec = z_drop @ z_drop.T (B^T = zd itself)
    k_mm<4><<<dim3(32, 32), 256, 0, stream>>>(zd, ZZ, zd, ZZ, ZZ,
        out + DECOFF, NN, nullptr, 0, nullptr, 0, nullptr, nullptr, nullptr);
}